// Round 11
// baseline (392.253 us; speedup 1.0000x reference)
//
#include <hip/hip_runtime.h>
#include <hip/hip_cooperative_groups.h>
#include <hip/hip_bf16.h>

namespace cg = cooperative_groups;

typedef unsigned short u16;
typedef unsigned int   u32;
typedef __attribute__((ext_vector_type(8))) short bf16x8;
typedef __attribute__((ext_vector_type(4))) float f32x4;

#define NB   64
#define NTX  2048
#define ND   256
#define NL   1024

#if __has_builtin(__builtin_amdgcn_exp2f)
#define EXP2F(x) __builtin_amdgcn_exp2f(x)
#else
#define EXP2F(x) exp2f(x)
#endif
#if __has_builtin(__builtin_amdgcn_rcpf)
#define RCPF(x) __builtin_amdgcn_rcpf(x)
#else
#define RCPF(x) (1.0f/(x))
#endif

__device__ __forceinline__ u16 f2bf(float f){
  union { float f; u32 u; } c; c.f = f;
  return (u16)((c.u + 0x7fffu + ((c.u >> 16) & 1u)) >> 16);
}
__device__ __forceinline__ u32 pk2(float a, float b){
  return (u32)f2bf(a) | ((u32)f2bf(b) << 16);
}
__device__ __forceinline__ float sigmf(float x){ return 1.f/(1.f+__expf(-x)); }
__device__ __forceinline__ float tanhf_fast(float x){
  x = fminf(fmaxf(x, -15.f), 15.f);
  float e = __expf(2.f*x);
  return (e - 1.f) / (e + 1.f);
}

struct MA {
  const float *enc, *pre_in, *h_r1, *h_r2, *c_r1, *c_r2,
              *cv_text, *cv, *h_text, *h_attn,
              *fc1_w, *fc1_b, *fc2_w, *fc2_b, *tWm, *tv,
              *t_wih, *t_whh, *t_bih, *t_bhh,
              *a_wih, *a_whh, *a_bih, *a_bhh,
              *ri_w, *ri_b, *l1_wih, *l1_whh, *l1_bih, *l1_bhh,
              *l2_wih, *l2_whh, *l2_bih, *l2_bhh, *mp_w;
  float *qp, *attnP, *x0, *x1, *x2, *xtext, *xattn, *htT, *haT, *htnT, *p1T;
  u16 *hb1, *hb2, *xrib, *x0b, *x1b, *x2b;
  float* out;
};

// LSTM layer body: 16 waves, block = 4 j-cols (j0 = blk*4). Rs = 16K floats.
__device__ __forceinline__ void lstm_stage(const MA& a, float* Rs,
    const float* __restrict__ Wih, const float* __restrict__ Whh,
    const u16* __restrict__ xb, const u16* __restrict__ hb,
    const float* __restrict__ bih, const float* __restrict__ bhh,
    const float* __restrict__ c_in, const float* __restrict__ xin,
    float* __restrict__ xout, u16* __restrict__ xoutb)
{
  const int tid = threadIdx.x, lane = tid & 63, w = tid >> 6;
  const int j0 = blockIdx.x * 4;
  const float* W = (w < 8) ? Wih : Whh;
  const u16*   X = (w < 8) ? xb  : hb;
  const int kbase = (w & 7) * 128;
  f32x4 acc[4];
  #pragma unroll
  for (int i = 0; i < 4; ++i) acc[i] = (f32x4){0.f,0.f,0.f,0.f};
  const int r16 = lane & 15;
  const int g = r16 >> 2, jq = r16 & 3;
  const float* wr = W + (size_t)(g*1024 + j0 + jq)*1024 + kbase + (lane >> 4)*8;
  #pragma unroll
  for (int t = 0; t < 4; ++t){
    float4 wa = *(const float4*)(wr + t*32);
    float4 wb = *(const float4*)(wr + t*32 + 4);
    union { bf16x8 v; uint4 u; } bf;
    bf.u.x = pk2(wa.x,wa.y); bf.u.y = pk2(wa.z,wa.w);
    bf.u.z = pk2(wb.x,wb.y); bf.u.w = pk2(wb.z,wb.w);
    #pragma unroll
    for (int fb = 0; fb < 4; ++fb){
      union { bf16x8 v; uint4 u; } af;
      af.u = *(const uint4*)(X + (size_t)(fb*16 + r16)*1024 + kbase + (lane >> 4)*8 + t*32);
      acc[fb] = __builtin_amdgcn_mfma_f32_16x16x32_bf16(af.v, bf.v, acc[fb], 0, 0, 0);
    }
  }
  #pragma unroll
  for (int fb = 0; fb < 4; ++fb)
    #pragma unroll
    for (int r = 0; r < 4; ++r)
      Rs[w*1024 + fb*256 + r*64 + ((lane + w*4) & 63)] = acc[fb][r];
  __syncthreads();
  if (tid < 256){
    const int b  = tid >> 2, jq2 = tid & 3;
    const int j  = j0 + jq2;
    const int fb = b >> 4, q = (b >> 2) & 3, reg = b & 3;
    float gate[4];
    #pragma unroll
    for (int gg = 0; gg < 4; ++gg){
      const int li = q*16 + gg*4 + jq2;
      float s = bih[gg*1024 + j] + bhh[gg*1024 + j];
      #pragma unroll
      for (int ww = 0; ww < 16; ++ww)
        s += Rs[ww*1024 + fb*256 + reg*64 + ((li + ww*4) & 63)];
      gate[gg] = s;
    }
    float ii = sigmf(gate[0]), ff = sigmf(gate[1]);
    float gv = tanhf_fast(gate[2]), oo = sigmf(gate[3]);
    float cc = ff * c_in[(size_t)b*1024 + j] + ii * gv;
    float hh = oo * tanhf_fast(cc);
    float xo = xin[(size_t)b*1024 + j] + hh;
    xout[(size_t)b*1024 + j]  = xo;
    xoutb[(size_t)b*1024 + j] = f2bf(xo);
  }
}

__global__ __launch_bounds__(1024) void k_mega(MA a)
{
  __shared__ char smem[65536];
  float* smemf = (float*)smem;
  cg::grid_group grid = cg::this_grid();
  const int tid = threadIdx.x, blk = blockIdx.x;
  const int lane = tid & 63, w = tid >> 6;
  const int vblk = blk*4 + (tid >> 8), vtid = tid & 255;

  // ---- Stage 1: transposes / fc1 / bf16 state copies ----
  if (vblk < 16){
    int ai = vblk >> 2, c0 = (vblk & 3)*64;
    const float* src = (ai==0)?a.cv_text:(ai==1)?a.cv:(ai==2)?a.h_text:a.h_attn;
    float* dst = (ai==0)?a.xtext:(ai==1)?a.xattn:(ai==2)?a.htT:a.haT;
    const int b = vtid & 63, cq = vtid >> 6;
    #pragma unroll
    for (int i = 0; i < 16; ++i){
      int c = c0 + cq + i*4;
      dst[(size_t)c*64 + b] = src[(size_t)b*256 + c];
    }
  } else if (vblk < 80){
    const int wv = vtid >> 6, ln = vtid & 63;
    const int n = (vblk - 16)*4 + wv;
    float acc = a.fc1_b[n];
    const float* wr = a.fc1_w + (size_t)n*80;
    const float* xr = a.pre_in + (size_t)ln*80;
    #pragma unroll
    for (int k = 0; k < 80; k += 4){
      float4 wq = *(const float4*)(wr + k);
      acc += wq.x*xr[k] + wq.y*xr[k+1] + wq.z*xr[k+2] + wq.w*xr[k+3];
    }
    a.p1T[n*64 + ln] = fmaxf(acc, 0.f);
  } else if (vblk < 144){
    const int t2 = vblk - 80;
    const float* src = (t2 < 32) ? a.h_r1 : a.h_r2;
    u16* dst = (t2 < 32) ? a.hb1 : a.hb2;
    const int base = (t2 & 31)*2048 + vtid*8;
    float4 p = *(const float4*)(src + base);
    float4 q = *(const float4*)(src + base + 4);
    uint4 o = { pk2(p.x,p.y), pk2(p.z,p.w), pk2(q.x,q.y), pk2(q.z,q.w) };
    *(uint4*)(dst + base) = o;
  }
  grid.sync();

  // ---- Stage 2: fc2 (vblk = n < 128), 4-wave k-split ----
  if (blk < 32){
    const int n = vblk;
    const int wv = vtid >> 6, ln = vtid & 63;
    float* red = smemf + (tid >> 8)*256;
    float acc = 0.f;
    const float* wr = a.fc2_w + (size_t)n*256 + wv*64;
    const float* xb = a.p1T + wv*64*64 + ln;
    #pragma unroll
    for (int k = 0; k < 64; k += 4){
      float4 wq = *(const float4*)(wr + k);
      acc += wq.x*xb[(k+0)*64] + wq.y*xb[(k+1)*64]
           + wq.z*xb[(k+2)*64] + wq.w*xb[(k+3)*64];
    }
    red[wv*64 + ln] = acc;
    __syncthreads();
    if (wv == 0){
      float v = fmaxf(red[ln]+red[64+ln]+red[128+ln]+red[192+ln] + a.fc2_b[n], 0.f);
      a.xtext[(size_t)(256+n)*64 + ln] = v;
      a.xattn[(size_t)(256+n)*64 + ln] = v;
    }
  }
  grid.sync();

  // ---- Stage 3: both GRUs, block = d, 16 waves (8 text + 8 attn) ----
  {
    const int d = blk;
    const int isA = (w >= 8), w8 = w & 7;
    const float* wih = isA ? a.a_wih : a.t_wih;
    const float* whh = isA ? a.a_whh : a.t_whh;
    const float* xT  = isA ? a.xattn : a.xtext;
    const float* hT  = isA ? a.haT   : a.htT;
    float* red = smemf;                       // [16][6][64]
    float s0=0.f,s1=0.f,s2=0.f,s3=0.f,s4=0.f,s5=0.f;
    {
      const float* wr = wih + (size_t)d*384       + w8*48;
      const float* wz = wih + (size_t)(256+d)*384 + w8*48;
      const float* wn = wih + (size_t)(512+d)*384 + w8*48;
      const float* xb = xT + w8*48*64 + lane;
      #pragma unroll 4
      for (int k = 0; k < 48; k += 4){
        float4 ar = *(const float4*)(wr + k);
        float4 az = *(const float4*)(wz + k);
        float4 an = *(const float4*)(wn + k);
        float x0 = xb[(k+0)*64], x1 = xb[(k+1)*64];
        float x2 = xb[(k+2)*64], x3 = xb[(k+3)*64];
        s0 += ar.x*x0 + ar.y*x1 + ar.z*x2 + ar.w*x3;
        s1 += az.x*x0 + az.y*x1 + az.z*x2 + az.w*x3;
        s2 += an.x*x0 + an.y*x1 + an.z*x2 + an.w*x3;
      }
    }
    {
      const float* vr = whh + (size_t)d*256       + w8*32;
      const float* vz = whh + (size_t)(256+d)*256 + w8*32;
      const float* vn = whh + (size_t)(512+d)*256 + w8*32;
      const float* hb = hT + w8*32*64 + lane;
      #pragma unroll 4
      for (int k = 0; k < 32; k += 4){
        float4 ar = *(const float4*)(vr + k);
        float4 az = *(const float4*)(vz + k);
        float4 an = *(const float4*)(vn + k);
        float h0 = hb[(k+0)*64], h1 = hb[(k+1)*64];
        float h2 = hb[(k+2)*64], h3 = hb[(k+3)*64];
        s3 += ar.x*h0 + ar.y*h1 + ar.z*h2 + ar.w*h3;
        s4 += az.x*h0 + az.y*h1 + az.z*h2 + az.w*h3;
        s5 += an.x*h0 + an.y*h1 + an.z*h2 + an.w*h3;
      }
    }
    red[(w*6+0)*64+lane]=s0; red[(w*6+1)*64+lane]=s1; red[(w*6+2)*64+lane]=s2;
    red[(w*6+3)*64+lane]=s3; red[(w*6+4)*64+lane]=s4; red[(w*6+5)*64+lane]=s5;
    __syncthreads();
    if (w == 0 || w == 8){
      const int base = (w == 8) ? 8 : 0;
      const float* bih = (w==8) ? a.a_bih : a.t_bih;
      const float* bhh = (w==8) ? a.a_bhh : a.t_bhh;
      const float* hT2 = (w==8) ? a.haT   : a.htT;
      float g6[6];
      #pragma unroll
      for (int i = 0; i < 6; ++i){
        float s = 0.f;
        #pragma unroll
        for (int ww = 0; ww < 8; ++ww) s += red[((base+ww)*6+i)*64 + lane];
        g6[i] = s;
      }
      float gir = bih[d]     + g6[0];
      float giz = bih[256+d] + g6[1];
      float gin = bih[512+d] + g6[2];
      float ghr = bhh[d]     + g6[3];
      float ghz = bhh[256+d] + g6[4];
      float ghn = bhh[512+d] + g6[5];
      float hd = hT2[d*64 + lane];
      float r  = sigmf(gir + ghr), z = sigmf(giz + ghz);
      float nn = tanhf_fast(gin + r*ghn);
      float hnew = (1.f - z)*nn + z*hd;
      if (w == 8) a.xrib[(size_t)lane*512 + 256 + d] = f2bf(hnew);
      else        a.htnT[(size_t)d*64 + lane]        = hnew;
    }
  }
  grid.sync();

  // ---- Stage 4: qp (vblk = d < 256), 4-wave k-split ----
  if (blk < 64){
    const int d = vblk;
    const int wv = vtid >> 6, ln = vtid & 63;
    float* red = smemf + (tid >> 8)*256;
    float acc = 0.f;
    const float* wr = a.tWm + (size_t)d*256 + wv*64;
    const float* xb = a.htnT + wv*64*64 + ln;
    #pragma unroll
    for (int k = 0; k < 64; k += 4){
      float4 wq = *(const float4*)(wr + k);
      acc += wq.x*xb[(k+0)*64] + wq.y*xb[(k+1)*64]
           + wq.z*xb[(k+2)*64] + wq.w*xb[(k+3)*64];
    }
    red[wv*64 + ln] = acc;
    __syncthreads();
    if (wv == 0)
      a.qp[ln*ND + d] = red[ln]+red[64+ln]+red[128+ln]+red[192+ln];
  }
  grid.sync();

  // ---- Stage 5: attention, block = (b, chgroup of 4 chunks), 16 waves ----
  {
    const int b = blk >> 2, chg = blk & 3;
    const float C2  = 2.885390082f;
    const float L2E = 1.4426950408f;
    float* qpL  = smemf;            // 256
    float* vL   = smemf + 256;      // 256
    float* ctxL = smemf + 512;      // 16*256
    float* sL   = smemf + 512 + 4096; // 16
    if (tid < 256){
      qpL[tid] = a.qp[b*ND + tid] * C2;
      vL[tid]  = a.tv[tid] * 2.f;
    }
    __syncthreads();
    const float q0 = qpL[lane*4+0], q1 = qpL[lane*4+1], q2 = qpL[lane*4+2], q3 = qpL[lane*4+3];
    const float v0 = vL[lane*4+0],  v1 = vL[lane*4+1],  v2 = vL[lane*4+2],  v3 = vL[lane*4+3];
    float vs = 0.5f*(v0 + v1 + v2 + v3);
    #pragma unroll
    for (int off = 1; off < 64; off <<= 1) vs += __shfl_xor(vs, off);
    const float VS = vs;
    float cx0=0.f, cx1=0.f, cx2=0.f, cx3=0.f, sacc=0.f;
    const float* base = a.enc + ((size_t)b*NTX + (size_t)chg*512 + w*32)*ND + lane*4;
    #pragma unroll 4
    for (int i = 0; i < 32; ++i){
      float4 ev = *(const float4*)(base + (size_t)i*ND);
      float e0 = ev.x, e1 = ev.y, e2 = ev.z, e3 = ev.w;
      float u0 = EXP2F(__builtin_fmaf(e0, C2, q0));
      float u1 = EXP2F(__builtin_fmaf(e1, C2, q1));
      float u2 = EXP2F(__builtin_fmaf(e2, C2, q2));
      float u3 = EXP2F(__builtin_fmaf(e3, C2, q3));
      float srow = v0*RCPF(u0 + 1.f) + v1*RCPF(u1 + 1.f)
                 + v2*RCPF(u2 + 1.f) + v3*RCPF(u3 + 1.f);
      #pragma unroll
      for (int off = 1; off < 64; off <<= 1) srow += __shfl_xor(srow, off);
      float ww = EXP2F((VS - srow) * L2E);
      sacc += ww;
      cx0 = __builtin_fmaf(ww, e0, cx0); cx1 = __builtin_fmaf(ww, e1, cx1);
      cx2 = __builtin_fmaf(ww, e2, cx2); cx3 = __builtin_fmaf(ww, e3, cx3);
    }
    ctxL[w*256 + lane*4+0]=cx0; ctxL[w*256 + lane*4+1]=cx1;
    ctxL[w*256 + lane*4+2]=cx2; ctxL[w*256 + lane*4+3]=cx3;
    if (lane == 0) sL[w] = sacc;
    __syncthreads();
    if (tid < 256){
      float c = 0.f;
      #pragma unroll
      for (int ww = 0; ww < 16; ++ww) c += ctxL[ww*256 + tid];
      a.attnP[(size_t)blk*257 + tid] = c;
      if (tid == 0){
        float s = 0.f;
        #pragma unroll
        for (int ww = 0; ww < 16; ++ww) s += sL[ww];
        a.attnP[(size_t)blk*257 + 256] = s;
      }
    }
  }
  grid.sync();

  // ---- Stage 6: mm_ri (blocks 0..63), inline attn reduce in LDS ----
  if (blk < 64){
    u16*   xctxb = (u16*)smem;                  // [64][256] bf16
    float* Rs    = (float*)(smem + 32768);      // [8][4][4][64]
    {
      const int b = tid >> 4, cg16 = tid & 15;
      float s = a.attnP[(size_t)(b*4+0)*257 + 256] + a.attnP[(size_t)(b*4+1)*257 + 256]
              + a.attnP[(size_t)(b*4+2)*257 + 256] + a.attnP[(size_t)(b*4+3)*257 + 256];
      float inv = RCPF(s);
      #pragma unroll
      for (int i = 0; i < 16; ++i){
        int c = cg16*16 + i;
        float v = a.attnP[(size_t)(b*4+0)*257 + c] + a.attnP[(size_t)(b*4+1)*257 + c]
                + a.attnP[(size_t)(b*4+2)*257 + c] + a.attnP[(size_t)(b*4+3)*257 + c];
        xctxb[b*256 + c] = f2bf(v * inv);
      }
    }
    __syncthreads();
    const int n0 = blk * 16;
    if (w < 8){
      f32x4 acc[4];
      #pragma unroll
      for (int i = 0; i < 4; ++i) acc[i] = (f32x4){0.f,0.f,0.f,0.f};
      const int kbase = w*64;
      const float* wr = a.ri_w + (size_t)(n0 + (lane & 15))*512 + kbase + (lane >> 4)*8;
      #pragma unroll
      for (int t = 0; t < 2; ++t){
        float4 wa = *(const float4*)(wr + t*32);
        float4 wb = *(const float4*)(wr + t*32 + 4);
        union { bf16x8 v; uint4 u; } bf;
        bf.u.x = pk2(wa.x,wa.y); bf.u.y = pk2(wa.z,wa.w);
        bf.u.z = pk2(wb.x,wb.y); bf.u.w = pk2(wb.z,wb.w);
        #pragma unroll
        for (int fb = 0; fb < 4; ++fb){
          union { bf16x8 v; uint4 u; } af;
          const int row = fb*16 + (lane & 15);
          if (w < 4)
            af.u = *(const uint4*)(xctxb + row*256 + kbase + (lane >> 4)*8 + t*32);
          else
            af.u = *(const uint4*)(a.xrib + (size_t)row*512 + kbase + (lane >> 4)*8 + t*32);
          acc[fb] = __builtin_amdgcn_mfma_f32_16x16x32_bf16(af.v, bf.v, acc[fb], 0, 0, 0);
        }
      }
      #pragma unroll
      for (int fb = 0; fb < 4; ++fb)
        #pragma unroll
        for (int r = 0; r < 4; ++r)
          Rs[w*1024 + fb*256 + r*64 + ((lane + w*4) & 63)] = acc[fb][r];
    }
    __syncthreads();
    if (tid < 256){
      const int b = tid >> 2, c4 = (tid & 3)*4;
      const int fb = b >> 4, q = (b >> 2) & 3, reg = b & 3;
      #pragma unroll
      for (int cc = 0; cc < 4; ++cc){
        const int c = c4 + cc;
        const int li = q*16 + c;
        float v = a.ri_b[n0 + c];
        #pragma unroll
        for (int ww = 0; ww < 8; ++ww)
          v += Rs[ww*1024 + fb*256 + reg*64 + ((li + ww*4) & 63)];
        a.x0[(size_t)b*1024 + n0 + c]  = v;
        a.x0b[(size_t)b*1024 + n0 + c] = f2bf(v);
      }
    }
  }
  grid.sync();

  // ---- Stage 7: LSTM layer 1 ----
  lstm_stage(a, smemf, a.l1_wih, a.l1_whh, a.x0b, a.hb1,
             a.l1_bih, a.l1_bhh, a.c_r1, a.x0, a.x1, a.x1b);
  grid.sync();

  // ---- Stage 8: LSTM layer 2 ----
  lstm_stage(a, smemf, a.l2_wih, a.l2_whh, a.x1b, a.hb2,
             a.l2_bih, a.l2_bhh, a.c_r2, a.x1, a.x2, a.x2b);
  grid.sync();

  // ---- Stage 9: mel projection (vblk = b < 64) ----
  if (blk < 16){
    const int b = vblk;
    float* xL = smemf + (tid >> 8)*1024;
    #pragma unroll
    for (int i = 0; i < 4; ++i){
      int j = vtid + 256*i;
      xL[j] = a.x2[(size_t)b*NL + j];
    }
    __syncthreads();
    if (vtid < 160){
      int m = vtid >> 1, r = vtid & 1;
      const float* row = a.mp_w + (size_t)(m*20 + r)*NL;
      float acc = 0.f;
      for (int k = 0; k < 1024; k += 4){
        float4 wq = *(const float4*)(row + k);
        acc += wq.x*xL[k] + wq.y*xL[k+1] + wq.z*xL[k+2] + wq.w*xL[k+3];
      }
      a.out[b*160 + vtid] = acc;
    }
  }
}

// ---------------------------------------------------------------------------
extern "C" void kernel_launch(void* const* d_in, const int* in_sizes, int n_in,
                              void* d_out, int out_size, void* d_ws, size_t ws_size,
                              hipStream_t stream)
{
  (void)in_sizes; (void)n_in; (void)out_size; (void)ws_size;
  MA a;
  a.enc     = (const float*)d_in[0];
  a.pre_in  = (const float*)d_in[2];
  a.h_text  = (const float*)d_in[3];
  a.h_attn  = (const float*)d_in[5];
  a.h_r1    = (const float*)d_in[6];
  a.h_r2    = (const float*)d_in[7];
  a.c_r1    = (const float*)d_in[8];
  a.c_r2    = (const float*)d_in[9];
  a.cv_text = (const float*)d_in[10];
  a.cv      = (const float*)d_in[12];
  a.fc1_w   = (const float*)d_in[13];
  a.fc1_b   = (const float*)d_in[14];
  a.fc2_w   = (const float*)d_in[15];
  a.fc2_b   = (const float*)d_in[16];
  a.tWm     = (const float*)d_in[17];
  a.tv      = (const float*)d_in[18];
  a.t_wih   = (const float*)d_in[21];
  a.t_whh   = (const float*)d_in[22];
  a.t_bih   = (const float*)d_in[23];
  a.t_bhh   = (const float*)d_in[24];
  a.a_wih   = (const float*)d_in[29];
  a.a_whh   = (const float*)d_in[30];
  a.a_bih   = (const float*)d_in[31];
  a.a_bhh   = (const float*)d_in[32];
  a.ri_w    = (const float*)d_in[33];
  a.ri_b    = (const float*)d_in[34];
  a.l1_wih  = (const float*)d_in[35];
  a.l1_whh  = (const float*)d_in[36];
  a.l1_bih  = (const float*)d_in[37];
  a.l1_bhh  = (const float*)d_in[38];
  a.l2_wih  = (const float*)d_in[39];
  a.l2_whh  = (const float*)d_in[40];
  a.l2_bih  = (const float*)d_in[41];
  a.l2_bhh  = (const float*)d_in[42];
  a.mp_w    = (const float*)d_in[43];

  float* ws = (float*)d_ws;
  a.qp    = ws;                       // 16384
  a.attnP = a.qp    + 16384;          // 256*257 = 65792
  a.x0    = a.attnP + 65792;          // 65536
  a.x1    = a.x0    + 65536;
  a.x2    = a.x1    + 65536;
  a.xtext = a.x2    + 65536;          // 24576
  a.xattn = a.xtext + 24576;          // 24576
  a.htT   = a.xattn + 24576;          // 16384
  a.haT   = a.htT   + 16384;
  a.htnT  = a.haT   + 16384;
  a.p1T   = a.htnT  + 16384;          // 16384
  a.hb1   = (u16*)(a.p1T + 16384);    // 65536 u16
  a.hb2   = a.hb1 + 65536;
  a.xrib  = a.hb2 + 65536;            // 64*512
  a.x0b   = a.xrib + 32768;           // 64*1024
  a.x1b   = a.x0b + 65536;
  a.x2b   = a.x1b + 65536;
  a.out   = (float*)d_out;

  void* args[] = { &a };
  hipLaunchCooperativeKernel((const void*)k_mega, dim3(256), dim3(1024),
                             args, 0, stream);
}

// Round 12
// 245.600 us; speedup vs baseline: 1.5971x; 1.5971x over previous
//
#include <hip/hip_runtime.h>
#include <hip/hip_bf16.h>

typedef unsigned short u16;
typedef unsigned int   u32;
typedef __attribute__((ext_vector_type(8))) short bf16x8;
typedef __attribute__((ext_vector_type(4))) float f32x4;

#define NB   64
#define NTX  2048
#define ND   256
#define NL   1024

#if __has_builtin(__builtin_amdgcn_exp2f)
#define EXP2F(x) __builtin_amdgcn_exp2f(x)
#else
#define EXP2F(x) exp2f(x)
#endif
#if __has_builtin(__builtin_amdgcn_rcpf)
#define RCPF(x) __builtin_amdgcn_rcpf(x)
#else
#define RCPF(x) (1.0f/(x))
#endif

__device__ __forceinline__ u16 f2bf(float f){
  union { float f; u32 u; } c; c.f = f;
  return (u16)((c.u + 0x7fffu + ((c.u >> 16) & 1u)) >> 16);
}
__device__ __forceinline__ u32 pk2(float a, float b){
  return (u32)f2bf(a) | ((u32)f2bf(b) << 16);
}
__device__ __forceinline__ float sigmf(float x){ return 1.f/(1.f+__expf(-x)); }
__device__ __forceinline__ float tanhf_fast(float x){
  x = fminf(fmaxf(x, -15.f), 15.f);
  float e = __expf(2.f*x);
  return (e - 1.f) / (e + 1.f);
}

// Lightweight grid barrier: 1 atomicAdd + relaxed spin per block, agent
// fences only at the quiesced barrier point. Counters zeroed by k_pre1.
__device__ __forceinline__ void gbar(int* cnt, int idx, int nb){
  __syncthreads();
  if (threadIdx.x == 0){
    __builtin_amdgcn_fence(__ATOMIC_RELEASE, "agent");
    __hip_atomic_fetch_add(&cnt[idx], 1, __ATOMIC_RELAXED, __HIP_MEMORY_SCOPE_AGENT);
    while (__hip_atomic_load(&cnt[idx], __ATOMIC_RELAXED, __HIP_MEMORY_SCOPE_AGENT) < nb)
      __builtin_amdgcn_s_sleep(4);
    __builtin_amdgcn_fence(__ATOMIC_ACQUIRE, "agent");
  }
  __syncthreads();
}

// ---------------------------------------------------------------------------
// F1: blocks 0..15 transposes; 16..79 fc1; 80..143 bf16 h copies; 144 zeroes cnt
// ---------------------------------------------------------------------------
__global__ __launch_bounds__(256) void k_pre1(
    const float* __restrict__ cv_text, const float* __restrict__ cv,
    const float* __restrict__ h_text,  const float* __restrict__ h_attn,
    const float* __restrict__ prenet_in,
    const float* __restrict__ fc1_w, const float* __restrict__ fc1_b,
    const float* __restrict__ h_r1, const float* __restrict__ h_r2,
    float* __restrict__ xtext, float* __restrict__ xattn,
    float* __restrict__ htT,  float* __restrict__ haT,
    float* __restrict__ p1T,
    u16* __restrict__ hb1, u16* __restrict__ hb2,
    int* __restrict__ cnt)
{
  __shared__ float ld[64][65];
  const int blk = blockIdx.x, tid = threadIdx.x;
  if (blk < 16){
    int a = blk >> 2; int c0 = (blk & 3)*64;
    const float* src = (a==0)?cv_text:(a==1)?cv:(a==2)?h_text:h_attn;
    float* dst = (a==0)?xtext:(a==1)?xattn:(a==2)?htT:haT;
    const int r = tid >> 2, q = tid & 3;
    #pragma unroll
    for (int i = 0; i < 4; ++i){
      float4 v = *(const float4*)(src + (size_t)r*256 + c0 + q*16 + i*4);
      ld[r][q*16+i*4+0] = v.x; ld[r][q*16+i*4+1] = v.y;
      ld[r][q*16+i*4+2] = v.z; ld[r][q*16+i*4+3] = v.w;
    }
    __syncthreads();
    const int cc = tid >> 2;
    #pragma unroll
    for (int i = 0; i < 4; ++i){
      int b0 = q*16 + i*4;
      float4 o = { ld[b0+0][cc], ld[b0+1][cc], ld[b0+2][cc], ld[b0+3][cc] };
      *(float4*)(dst + (size_t)(c0+cc)*64 + b0) = o;
    }
  } else if (blk < 80){
    const int wave = tid >> 6, lane = tid & 63;
    const int n = (blk - 16)*4 + wave;
    float acc = fc1_b[n];
    const float* wr = fc1_w + (size_t)n*80;
    const float* xr = prenet_in + (size_t)lane*80;
    #pragma unroll
    for (int k = 0; k < 80; k += 4){
      float4 w = *(const float4*)(wr + k);
      acc += w.x*xr[k] + w.y*xr[k+1] + w.z*xr[k+2] + w.w*xr[k+3];
    }
    p1T[n*64 + lane] = fmaxf(acc, 0.f);
  } else if (blk < 144){
    const int t2 = blk - 80;
    const float* src = (t2 < 32) ? h_r1 : h_r2;
    u16* dst = (t2 < 32) ? hb1 : hb2;
    const int base = (t2 & 31)*2048 + tid*8;
    float4 a = *(const float4*)(src + base);
    float4 b = *(const float4*)(src + base + 4);
    uint4 o = { pk2(a.x,a.y), pk2(a.z,a.w), pk2(b.x,b.y), pk2(b.z,b.w) };
    *(uint4*)(dst + base) = o;
  } else {
    if (tid < 8) cnt[tid] = 0;
  }
}

// F2: fc2, 128 blocks (block = n), 4-wave k-split + LDS reduce.
__global__ __launch_bounds__(256) void k_pre2(
    const float* __restrict__ p1T,
    const float* __restrict__ fc2_w, const float* __restrict__ fc2_b,
    float* __restrict__ xtext, float* __restrict__ xattn)
{
  const int tid = threadIdx.x, w = tid >> 6, lane = tid & 63;
  const int n = blockIdx.x;
  __shared__ float red[4][64];
  float acc = 0.f;
  const float* wr = fc2_w + (size_t)n*256 + w*64;
  const float* xb = p1T + w*64*64 + lane;
  #pragma unroll
  for (int k = 0; k < 64; k += 4){
    float4 wv = *(const float4*)(wr + k);
    acc += wv.x*xb[(k+0)*64] + wv.y*xb[(k+1)*64]
         + wv.z*xb[(k+2)*64] + wv.w*xb[(k+3)*64];
  }
  red[w][lane] = acc;
  __syncthreads();
  if (w == 0){
    float v = fmaxf(red[0][lane]+red[1][lane]+red[2][lane]+red[3][lane] + fc2_b[n], 0.f);
    xtext[(size_t)(256+n)*64 + lane] = v;
    xattn[(size_t)(256+n)*64 + lane] = v;
  }
}

// F3: GRUs. 512 blocks x 512 threads (8 waves k-split + LDS reduce).
__global__ __launch_bounds__(512) void k_gru(
    const float* __restrict__ t_wih, const float* __restrict__ t_whh,
    const float* __restrict__ t_bih, const float* __restrict__ t_bhh,
    const float* __restrict__ a_wih, const float* __restrict__ a_whh,
    const float* __restrict__ a_bih, const float* __restrict__ a_bhh,
    const float* __restrict__ xtext, const float* __restrict__ xattn,
    const float* __restrict__ htT,  const float* __restrict__ haT,
    float* __restrict__ htnT, u16* __restrict__ xrib)
{
  const int tid = threadIdx.x, w = tid >> 6, lane = tid & 63;
  const int isA = blockIdx.x >= 256;
  const int d = blockIdx.x & 255;
  const float* wih = isA ? a_wih : t_wih;
  const float* whh = isA ? a_whh : t_whh;
  const float* xT  = isA ? xattn : xtext;
  const float* hT  = isA ? haT   : htT;
  __shared__ float red[8][6][64];
  float s0=0.f,s1=0.f,s2=0.f,s3=0.f,s4=0.f,s5=0.f;
  {
    const float* wr = wih + (size_t)d*384       + w*48;
    const float* wz = wih + (size_t)(256+d)*384 + w*48;
    const float* wn = wih + (size_t)(512+d)*384 + w*48;
    const float* xb = xT + w*48*64 + lane;
    #pragma unroll 4
    for (int k = 0; k < 48; k += 4){
      float4 ar = *(const float4*)(wr + k);
      float4 az = *(const float4*)(wz + k);
      float4 an = *(const float4*)(wn + k);
      float x0 = xb[(k+0)*64], x1 = xb[(k+1)*64];
      float x2 = xb[(k+2)*64], x3 = xb[(k+3)*64];
      s0 += ar.x*x0 + ar.y*x1 + ar.z*x2 + ar.w*x3;
      s1 += az.x*x0 + az.y*x1 + az.z*x2 + az.w*x3;
      s2 += an.x*x0 + an.y*x1 + an.z*x2 + an.w*x3;
    }
  }
  {
    const float* vr = whh + (size_t)d*256       + w*32;
    const float* vz = whh + (size_t)(256+d)*256 + w*32;
    const float* vn = whh + (size_t)(512+d)*256 + w*32;
    const float* hb = hT + w*32*64 + lane;
    #pragma unroll 4
    for (int k = 0; k < 32; k += 4){
      float4 ar = *(const float4*)(vr + k);
      float4 az = *(const float4*)(vz + k);
      float4 an = *(const float4*)(vn + k);
      float h0 = hb[(k+0)*64], h1 = hb[(k+1)*64];
      float h2 = hb[(k+2)*64], h3 = hb[(k+3)*64];
      s3 += ar.x*h0 + ar.y*h1 + ar.z*h2 + ar.w*h3;
      s4 += az.x*h0 + az.y*h1 + az.z*h2 + az.w*h3;
      s5 += an.x*h0 + an.y*h1 + an.z*h2 + an.w*h3;
    }
  }
  red[w][0][lane]=s0; red[w][1][lane]=s1; red[w][2][lane]=s2;
  red[w][3][lane]=s3; red[w][4][lane]=s4; red[w][5][lane]=s5;
  __syncthreads();
  if (w == 0){
    const float* bih = isA ? a_bih : t_bih;
    const float* bhh = isA ? a_bhh : t_bhh;
    float g6[6];
    #pragma unroll
    for (int i = 0; i < 6; ++i){
      float a = 0.f;
      #pragma unroll
      for (int ww = 0; ww < 8; ++ww) a += red[ww][i][lane];
      g6[i] = a;
    }
    float gir = bih[d]     + g6[0];
    float giz = bih[256+d] + g6[1];
    float gin = bih[512+d] + g6[2];
    float ghr = bhh[d]     + g6[3];
    float ghz = bhh[256+d] + g6[4];
    float ghn = bhh[512+d] + g6[5];
    float hd = hT[d*64 + lane];
    float r  = sigmf(gir + ghr), z = sigmf(giz + ghz);
    float nn = tanhf_fast(gin + r*ghn);
    float hnew = (1.f - z)*nn + z*hd;
    if (isA) xrib[(size_t)lane*512 + 256 + d] = f2bf(hnew);
    else     htnT[(size_t)d*64 + lane]        = hnew;
  }
}

// F4: qp. 256 blocks (block = d), 4-wave k-split + reduce.
__global__ __launch_bounds__(256) void k_qp(
    const float* __restrict__ tWm, const float* __restrict__ htnT,
    float* __restrict__ qp)
{
  const int tid = threadIdx.x, w = tid >> 6, lane = tid & 63;
  const int d = blockIdx.x;
  __shared__ float red[4][64];
  float acc = 0.f;
  const float* wr = tWm + (size_t)d*256 + w*64;
  const float* xb = htnT + w*64*64 + lane;
  #pragma unroll
  for (int k = 0; k < 64; k += 4){
    float4 wv = *(const float4*)(wr + k);
    acc += wv.x*xb[(k+0)*64] + wv.y*xb[(k+1)*64]
         + wv.z*xb[(k+2)*64] + wv.w*xb[(k+3)*64];
  }
  red[w][lane] = acc;
  __syncthreads();
  if (w == 0)
    qp[lane*ND + d] = red[0][lane]+red[1][lane]+red[2][lane]+red[3][lane];
}

// ---------------------------------------------------------------------------
// Back half: attn -> (red+ri) -> lstm1 -> lstm2 -> mels in ONE cooperative
// kernel, custom barriers. 256 blocks x 1024 threads. Stage code = R11 mega
// (correctness-verified), grid.sync replaced by gbar.
// ---------------------------------------------------------------------------
struct BA {
  const float *enc, *qp, *tv, *ri_w, *ri_b,
              *l1_wih, *l1_whh, *l1_bih, *l1_bhh, *c_r1,
              *l2_wih, *l2_whh, *l2_bih, *l2_bhh, *c_r2, *mp_w;
  float *attnP, *x0, *x1, *x2;
  u16 *xrib, *x0b, *x1b, *x2b, *hb1, *hb2;
  float* out;
  int* cnt;
};

__device__ __forceinline__ void lstm_stage(float* Rs,
    const float* __restrict__ Wih, const float* __restrict__ Whh,
    const u16* __restrict__ xb, const u16* __restrict__ hb,
    const float* __restrict__ bih, const float* __restrict__ bhh,
    const float* __restrict__ c_in, const float* __restrict__ xin,
    float* __restrict__ xout, u16* __restrict__ xoutb)
{
  const int tid = threadIdx.x, lane = tid & 63, w = tid >> 6;
  const int j0 = blockIdx.x * 4;
  const float* W = (w < 8) ? Wih : Whh;
  const u16*   X = (w < 8) ? xb  : hb;
  const int kbase = (w & 7) * 128;
  f32x4 acc[4];
  #pragma unroll
  for (int i = 0; i < 4; ++i) acc[i] = (f32x4){0.f,0.f,0.f,0.f};
  const int r16 = lane & 15;
  const int g = r16 >> 2, jq = r16 & 3;
  const float* wr = W + (size_t)(g*1024 + j0 + jq)*1024 + kbase + (lane >> 4)*8;
  #pragma unroll
  for (int t = 0; t < 4; ++t){
    float4 wa = *(const float4*)(wr + t*32);
    float4 wb = *(const float4*)(wr + t*32 + 4);
    union { bf16x8 v; uint4 u; } bf;
    bf.u.x = pk2(wa.x,wa.y); bf.u.y = pk2(wa.z,wa.w);
    bf.u.z = pk2(wb.x,wb.y); bf.u.w = pk2(wb.z,wb.w);
    #pragma unroll
    for (int fb = 0; fb < 4; ++fb){
      union { bf16x8 v; uint4 u; } af;
      af.u = *(const uint4*)(X + (size_t)(fb*16 + r16)*1024 + kbase + (lane >> 4)*8 + t*32);
      acc[fb] = __builtin_amdgcn_mfma_f32_16x16x32_bf16(af.v, bf.v, acc[fb], 0, 0, 0);
    }
  }
  #pragma unroll
  for (int fb = 0; fb < 4; ++fb)
    #pragma unroll
    for (int r = 0; r < 4; ++r)
      Rs[w*1024 + fb*256 + r*64 + ((lane + w*4) & 63)] = acc[fb][r];
  __syncthreads();
  if (tid < 256){
    const int b  = tid >> 2, jq2 = tid & 3;
    const int j  = j0 + jq2;
    const int fb = b >> 4, q = (b >> 2) & 3, reg = b & 3;
    float gate[4];
    #pragma unroll
    for (int gg = 0; gg < 4; ++gg){
      const int li = q*16 + gg*4 + jq2;
      float s = bih[gg*1024 + j] + bhh[gg*1024 + j];
      #pragma unroll
      for (int ww = 0; ww < 16; ++ww)
        s += Rs[ww*1024 + fb*256 + reg*64 + ((li + ww*4) & 63)];
      gate[gg] = s;
    }
    float ii = sigmf(gate[0]), ff = sigmf(gate[1]);
    float gv = tanhf_fast(gate[2]), oo = sigmf(gate[3]);
    float cc = ff * c_in[(size_t)b*1024 + j] + ii * gv;
    float hh = oo * tanhf_fast(cc);
    float xo = xin[(size_t)b*1024 + j] + hh;
    xout[(size_t)b*1024 + j]  = xo;
    xoutb[(size_t)b*1024 + j] = f2bf(xo);
  }
}

__global__ __launch_bounds__(1024) void k_back(BA a)
{
  __shared__ char smem[65536];
  float* smemf = (float*)smem;
  const int tid = threadIdx.x, blk = blockIdx.x;
  const int lane = tid & 63, w = tid >> 6;
  const int vblk = blk*4 + (tid >> 8), vtid = tid & 255;

  // ---- Stage A: attention, block = (b, chgroup of 512 t), 16 waves ----
  {
    const int b = blk >> 2, chg = blk & 3;
    const float C2  = 2.885390082f;
    const float L2E = 1.4426950408f;
    float* qpL  = smemf;
    float* vL   = smemf + 256;
    float* ctxL = smemf + 512;
    float* sL   = smemf + 512 + 4096;
    if (tid < 256){
      qpL[tid] = a.qp[b*ND + tid] * C2;
      vL[tid]  = a.tv[tid] * 2.f;
    }
    __syncthreads();
    const float q0 = qpL[lane*4+0], q1 = qpL[lane*4+1], q2 = qpL[lane*4+2], q3 = qpL[lane*4+3];
    const float v0 = vL[lane*4+0],  v1 = vL[lane*4+1],  v2 = vL[lane*4+2],  v3 = vL[lane*4+3];
    float vs = 0.5f*(v0 + v1 + v2 + v3);
    #pragma unroll
    for (int off = 1; off < 64; off <<= 1) vs += __shfl_xor(vs, off);
    const float VS = vs;
    float cx0=0.f, cx1=0.f, cx2=0.f, cx3=0.f, sacc=0.f;
    const float* base = a.enc + ((size_t)b*NTX + (size_t)chg*512 + w*32)*ND + lane*4;
    #pragma unroll 4
    for (int i = 0; i < 32; ++i){
      float4 ev = *(const float4*)(base + (size_t)i*ND);
      float e0 = ev.x, e1 = ev.y, e2 = ev.z, e3 = ev.w;
      float u0 = EXP2F(__builtin_fmaf(e0, C2, q0));
      float u1 = EXP2F(__builtin_fmaf(e1, C2, q1));
      float u2 = EXP2F(__builtin_fmaf(e2, C2, q2));
      float u3 = EXP2F(__builtin_fmaf(e3, C2, q3));
      float srow = v0*RCPF(u0 + 1.f) + v1*RCPF(u1 + 1.f)
                 + v2*RCPF(u2 + 1.f) + v3*RCPF(u3 + 1.f);
      #pragma unroll
      for (int off = 1; off < 64; off <<= 1) srow += __shfl_xor(srow, off);
      float ww = EXP2F((VS - srow) * L2E);
      sacc += ww;
      cx0 = __builtin_fmaf(ww, e0, cx0); cx1 = __builtin_fmaf(ww, e1, cx1);
      cx2 = __builtin_fmaf(ww, e2, cx2); cx3 = __builtin_fmaf(ww, e3, cx3);
    }
    ctxL[w*256 + lane*4+0]=cx0; ctxL[w*256 + lane*4+1]=cx1;
    ctxL[w*256 + lane*4+2]=cx2; ctxL[w*256 + lane*4+3]=cx3;
    if (lane == 0) sL[w] = sacc;
    __syncthreads();
    if (tid < 256){
      float c = 0.f;
      #pragma unroll
      for (int ww = 0; ww < 16; ++ww) c += ctxL[ww*256 + tid];
      a.attnP[(size_t)blk*257 + tid] = c;
      if (tid == 0){
        float s = 0.f;
        #pragma unroll
        for (int ww = 0; ww < 16; ++ww) s += sL[ww];
        a.attnP[(size_t)blk*257 + 256] = s;
      }
    }
  }
  gbar(a.cnt, 0, 256);

  // ---- Stage B: red + ri (blocks 0..63) ----
  if (blk < 64){
    u16*   xctxb = (u16*)smem;
    float* Rs    = (float*)(smem + 32768);
    {
      const int b = tid >> 4, cg16 = tid & 15;
      float s = a.attnP[(size_t)(b*4+0)*257 + 256] + a.attnP[(size_t)(b*4+1)*257 + 256]
              + a.attnP[(size_t)(b*4+2)*257 + 256] + a.attnP[(size_t)(b*4+3)*257 + 256];
      float inv = RCPF(s);
      #pragma unroll
      for (int i = 0; i < 16; ++i){
        int c = cg16*16 + i;
        float v = a.attnP[(size_t)(b*4+0)*257 + c] + a.attnP[(size_t)(b*4+1)*257 + c]
                + a.attnP[(size_t)(b*4+2)*257 + c] + a.attnP[(size_t)(b*4+3)*257 + c];
        xctxb[b*256 + c] = f2bf(v * inv);
      }
    }
    __syncthreads();
    const int n0 = blk * 16;
    if (w < 8){
      f32x4 acc[4];
      #pragma unroll
      for (int i = 0; i < 4; ++i) acc[i] = (f32x4){0.f,0.f,0.f,0.f};
      const int kbase = w*64;
      const float* wr = a.ri_w + (size_t)(n0 + (lane & 15))*512 + kbase + (lane >> 4)*8;
      #pragma unroll
      for (int t = 0; t < 2; ++t){
        float4 wa = *(const float4*)(wr + t*32);
        float4 wb = *(const float4*)(wr + t*32 + 4);
        union { bf16x8 v; uint4 u; } bf;
        bf.u.x = pk2(wa.x,wa.y); bf.u.y = pk2(wa.z,wa.w);
        bf.u.z = pk2(wb.x,wb.y); bf.u.w = pk2(wb.z,wb.w);
        #pragma unroll
        for (int fb = 0; fb < 4; ++fb){
          union { bf16x8 v; uint4 u; } af;
          const int row = fb*16 + (lane & 15);
          if (w < 4)
            af.u = *(const uint4*)(xctxb + row*256 + kbase + (lane >> 4)*8 + t*32);
          else
            af.u = *(const uint4*)(a.xrib + (size_t)row*512 + kbase + (lane >> 4)*8 + t*32);
          acc[fb] = __builtin_amdgcn_mfma_f32_16x16x32_bf16(af.v, bf.v, acc[fb], 0, 0, 0);
        }
      }
      #pragma unroll
      for (int fb = 0; fb < 4; ++fb)
        #pragma unroll
        for (int r = 0; r < 4; ++r)
          Rs[w*1024 + fb*256 + r*64 + ((lane + w*4) & 63)] = acc[fb][r];
    }
    __syncthreads();
    if (tid < 256){
      const int b = tid >> 2, c4 = (tid & 3)*4;
      const int fb = b >> 4, q = (b >> 2) & 3, reg = b & 3;
      #pragma unroll
      for (int cc = 0; cc < 4; ++cc){
        const int c = c4 + cc;
        const int li = q*16 + c;
        float v = a.ri_b[n0 + c];
        #pragma unroll
        for (int ww = 0; ww < 8; ++ww)
          v += Rs[ww*1024 + fb*256 + reg*64 + ((li + ww*4) & 63)];
        a.x0[(size_t)b*1024 + n0 + c]  = v;
        a.x0b[(size_t)b*1024 + n0 + c] = f2bf(v);
      }
    }
  }
  gbar(a.cnt, 1, 256);

  // ---- Stage C/D: LSTM layers ----
  lstm_stage(smemf, a.l1_wih, a.l1_whh, a.x0b, a.hb1,
             a.l1_bih, a.l1_bhh, a.c_r1, a.x0, a.x1, a.x1b);
  gbar(a.cnt, 2, 256);
  lstm_stage(smemf, a.l2_wih, a.l2_whh, a.x1b, a.hb2,
             a.l2_bih, a.l2_bhh, a.c_r2, a.x1, a.x2, a.x2b);
  gbar(a.cnt, 3, 256);

  // ---- Stage E: mel projection (blocks 0..15, vblk = b) ----
  if (blk < 16){
    const int b = vblk;
    float* xL = smemf + (tid >> 8)*1024;
    #pragma unroll
    for (int i = 0; i < 4; ++i){
      int j = vtid + 256*i;
      xL[j] = a.x2[(size_t)b*NL + j];
    }
    __syncthreads();
    if (vtid < 160){
      int m = vtid >> 1, r = vtid & 1;
      const float* row = a.mp_w + (size_t)(m*20 + r)*NL;
      float acc = 0.f;
      for (int k = 0; k < 1024; k += 4){
        float4 wq = *(const float4*)(row + k);
        acc += wq.x*xL[k] + wq.y*xL[k+1] + wq.z*xL[k+2] + wq.w*xL[k+3];
      }
      a.out[b*160 + vtid] = acc;
    }
  }
}

// ---------------------------------------------------------------------------
extern "C" void kernel_launch(void* const* d_in, const int* in_sizes, int n_in,
                              void* d_out, int out_size, void* d_ws, size_t ws_size,
                              hipStream_t stream)
{
  (void)in_sizes; (void)n_in; (void)out_size; (void)ws_size;
  const float* enc     = (const float*)d_in[0];
  const float* pre_in  = (const float*)d_in[2];
  const float* h_text  = (const float*)d_in[3];
  const float* h_attn  = (const float*)d_in[5];
  const float* h_r1    = (const float*)d_in[6];
  const float* h_r2    = (const float*)d_in[7];
  const float* c_r1    = (const float*)d_in[8];
  const float* c_r2    = (const float*)d_in[9];
  const float* cv_text = (const float*)d_in[10];
  const float* cv      = (const float*)d_in[12];
  const float* fc1_w   = (const float*)d_in[13];
  const float* fc1_b   = (const float*)d_in[14];
  const float* fc2_w   = (const float*)d_in[15];
  const float* fc2_b   = (const float*)d_in[16];
  const float* tWm     = (const float*)d_in[17];
  const float* tv      = (const float*)d_in[18];
  const float* t_wih   = (const float*)d_in[21];
  const float* t_whh   = (const float*)d_in[22];
  const float* t_bih   = (const float*)d_in[23];
  const float* t_bhh   = (const float*)d_in[24];
  const float* a_wih   = (const float*)d_in[29];
  const float* a_whh   = (const float*)d_in[30];
  const float* a_bih   = (const float*)d_in[31];
  const float* a_bhh   = (const float*)d_in[32];
  const float* ri_w    = (const float*)d_in[33];
  const float* ri_b    = (const float*)d_in[34];
  const float* l1_wih  = (const float*)d_in[35];
  const float* l1_whh  = (const float*)d_in[36];
  const float* l1_bih  = (const float*)d_in[37];
  const float* l1_bhh  = (const float*)d_in[38];
  const float* l2_wih  = (const float*)d_in[39];
  const float* l2_whh  = (const float*)d_in[40];
  const float* l2_bih  = (const float*)d_in[41];
  const float* l2_bhh  = (const float*)d_in[42];
  const float* mp_w    = (const float*)d_in[43];

  float* ws    = (float*)d_ws;
  float* qp    = ws;                    // 16384
  float* attnP = qp    + 16384;         // 256*257 = 65792
  float* x0    = attnP + 65792;         // 65536
  float* x1    = x0    + 65536;
  float* x2    = x1    + 65536;
  float* xtext = x2    + 65536;         // 24576
  float* xattn = xtext + 24576;         // 24576
  float* htT   = xattn + 24576;         // 16384
  float* haT   = htT   + 16384;
  float* htnT  = haT   + 16384;
  float* p1T   = htnT  + 16384;         // 16384
  u16*   hb1   = (u16*)(p1T + 16384);   // 65536 u16
  u16*   hb2   = hb1 + 65536;
  u16*   xrib  = hb2 + 65536;           // 64*512
  u16*   x0b   = xrib + 32768;          // 64*1024
  u16*   x1b   = x0b + 65536;
  u16*   x2b   = x1b + 65536;
  int*   cnt   = (int*)(x2b + 65536);   // 8 ints

  k_pre1<<<145, 256, 0, stream>>>(cv_text, cv, h_text, h_attn,
      pre_in, fc1_w, fc1_b, h_r1, h_r2,
      xtext, xattn, htT, haT, p1T, hb1, hb2, cnt);
  k_pre2<<<128, 256, 0, stream>>>(p1T, fc2_w, fc2_b, xtext, xattn);
  k_gru<<<512, 512, 0, stream>>>(t_wih, t_whh, t_bih, t_bhh,
      a_wih, a_whh, a_bih, a_bhh, xtext, xattn, htT, haT, htnT, xrib);
  k_qp<<<256, 256, 0, stream>>>(tWm, htnT, qp);

  BA a;
  a.enc = enc; a.qp = qp; a.tv = tv; a.ri_w = ri_w; a.ri_b = ri_b;
  a.l1_wih = l1_wih; a.l1_whh = l1_whh; a.l1_bih = l1_bih; a.l1_bhh = l1_bhh; a.c_r1 = c_r1;
  a.l2_wih = l2_wih; a.l2_whh = l2_whh; a.l2_bih = l2_bih; a.l2_bhh = l2_bhh; a.c_r2 = c_r2;
  a.mp_w = mp_w;
  a.attnP = attnP; a.x0 = x0; a.x1 = x1; a.x2 = x2;
  a.xrib = xrib; a.x0b = x0b; a.x1b = x1b; a.x2b = x2b;
  a.hb1 = hb1; a.hb2 = hb2;
  a.out = (float*)d_out;
  a.cnt = cnt;

  void* args[] = { &a };
  hipLaunchCooperativeKernel((const void*)k_back, dim3(256), dim3(1024),
                             args, 0, stream);
}

// Round 13
// 124.467 us; speedup vs baseline: 3.1515x; 1.9732x over previous
//
#include <hip/hip_runtime.h>
#include <hip/hip_bf16.h>

typedef unsigned short u16;
typedef unsigned int   u32;
typedef __attribute__((ext_vector_type(8))) short bf16x8;
typedef __attribute__((ext_vector_type(4))) float f32x4;

#define NB   64
#define NTX  2048
#define ND   256
#define NL   1024

#if __has_builtin(__builtin_amdgcn_exp2f)
#define EXP2F(x) __builtin_amdgcn_exp2f(x)
#else
#define EXP2F(x) exp2f(x)
#endif
#if __has_builtin(__builtin_amdgcn_rcpf)
#define RCPF(x) __builtin_amdgcn_rcpf(x)
#else
#define RCPF(x) (1.0f/(x))
#endif

__device__ __forceinline__ u16 f2bf(float f){
  union { float f; u32 u; } c; c.f = f;
  return (u16)((c.u + 0x7fffu + ((c.u >> 16) & 1u)) >> 16);
}
__device__ __forceinline__ u32 pk2(float a, float b){
  return (u32)f2bf(a) | ((u32)f2bf(b) << 16);
}
__device__ __forceinline__ float sigmf(float x){ return 1.f/(1.f+__expf(-x)); }
__device__ __forceinline__ float tanhf_fast(float x){
  x = fminf(fmaxf(x, -15.f), 15.f);
  float e = __expf(2.f*x);
  return (e - 1.f) / (e + 1.f);
}
__device__ __forceinline__ float dot_rowf(const float* __restrict__ row,
                                          const float* __restrict__ x, int K4){
  float acc = 0.f;
  for (int j = 0; j < K4; ++j){
    float4 w = *(const float4*)(row + j*4);
    const float* xp = x + j*4;
    acc += w.x*xp[0] + w.y*xp[1] + w.z*xp[2] + w.w*xp[3];
  }
  return acc;
}

// ---------------------------------------------------------------------------
// F1: blocks 0..15  : transposes [64][256] -> [256][64]
//     blocks 16..79 : fc1 batch-on-lanes -> p1T [256][64]
//     blocks 80..143: h_r1/h_r2 fp32 -> bf16 copies
// ---------------------------------------------------------------------------
__global__ __launch_bounds__(256) void k_pre1(
    const float* __restrict__ cv_text, const float* __restrict__ cv,
    const float* __restrict__ h_text,  const float* __restrict__ h_attn,
    const float* __restrict__ prenet_in,
    const float* __restrict__ fc1_w, const float* __restrict__ fc1_b,
    const float* __restrict__ h_r1, const float* __restrict__ h_r2,
    float* __restrict__ xtext, float* __restrict__ xattn,
    float* __restrict__ htT,  float* __restrict__ haT,
    float* __restrict__ p1T,
    u16* __restrict__ hb1, u16* __restrict__ hb2)
{
  __shared__ float ld[64][65];
  const int blk = blockIdx.x, tid = threadIdx.x;
  if (blk < 16){
    int a = blk >> 2; int c0 = (blk & 3)*64;
    const float* src = (a==0)?cv_text:(a==1)?cv:(a==2)?h_text:h_attn;
    float* dst = (a==0)?xtext:(a==1)?xattn:(a==2)?htT:haT;
    const int r = tid >> 2, q = tid & 3;
    #pragma unroll
    for (int i = 0; i < 4; ++i){
      float4 v = *(const float4*)(src + (size_t)r*256 + c0 + q*16 + i*4);
      ld[r][q*16+i*4+0] = v.x; ld[r][q*16+i*4+1] = v.y;
      ld[r][q*16+i*4+2] = v.z; ld[r][q*16+i*4+3] = v.w;
    }
    __syncthreads();
    const int cc = tid >> 2;
    #pragma unroll
    for (int i = 0; i < 4; ++i){
      int b0 = q*16 + i*4;
      float4 o = { ld[b0+0][cc], ld[b0+1][cc], ld[b0+2][cc], ld[b0+3][cc] };
      *(float4*)(dst + (size_t)(c0+cc)*64 + b0) = o;
    }
  } else if (blk < 80){
    const int wave = tid >> 6, lane = tid & 63;
    const int n = (blk - 16)*4 + wave;
    float acc = fc1_b[n];
    const float* wr = fc1_w + (size_t)n*80;
    const float* xr = prenet_in + (size_t)lane*80;
    #pragma unroll
    for (int k = 0; k < 80; k += 4){
      float4 w = *(const float4*)(wr + k);
      acc += w.x*xr[k] + w.y*xr[k+1] + w.z*xr[k+2] + w.w*xr[k+3];
    }
    p1T[n*64 + lane] = fmaxf(acc, 0.f);
  } else {
    const int t2 = blk - 80;
    const float* src = (t2 < 32) ? h_r1 : h_r2;
    u16* dst = (t2 < 32) ? hb1 : hb2;
    const int base = (t2 & 31)*2048 + tid*8;
    float4 a = *(const float4*)(src + base);
    float4 b = *(const float4*)(src + base + 4);
    uint4 o = { pk2(a.x,a.y), pk2(a.z,a.w), pk2(b.x,b.y), pk2(b.z,b.w) };
    *(uint4*)(dst + base) = o;
  }
}

// F2: fc2, 128 blocks (block = n), 4-wave k-split + LDS reduce.
__global__ __launch_bounds__(256) void k_pre2(
    const float* __restrict__ p1T,
    const float* __restrict__ fc2_w, const float* __restrict__ fc2_b,
    float* __restrict__ xtext, float* __restrict__ xattn)
{
  const int tid = threadIdx.x, w = tid >> 6, lane = tid & 63;
  const int n = blockIdx.x;
  __shared__ float red[4][64];
  float acc = 0.f;
  const float* wr = fc2_w + (size_t)n*256 + w*64;
  const float* xb = p1T + w*64*64 + lane;
  #pragma unroll
  for (int k = 0; k < 64; k += 4){
    float4 wv = *(const float4*)(wr + k);
    acc += wv.x*xb[(k+0)*64] + wv.y*xb[(k+1)*64]
         + wv.z*xb[(k+2)*64] + wv.w*xb[(k+3)*64];
  }
  red[w][lane] = acc;
  __syncthreads();
  if (w == 0){
    float v = fmaxf(red[0][lane]+red[1][lane]+red[2][lane]+red[3][lane] + fc2_b[n], 0.f);
    xtext[(size_t)(256+n)*64 + lane] = v;
    xattn[(size_t)(256+n)*64 + lane] = v;
  }
}

// F3: GRUs. 512 blocks x 512 threads (8 waves k-split + LDS reduce).
__global__ __launch_bounds__(512) void k_gru(
    const float* __restrict__ t_wih, const float* __restrict__ t_whh,
    const float* __restrict__ t_bih, const float* __restrict__ t_bhh,
    const float* __restrict__ a_wih, const float* __restrict__ a_whh,
    const float* __restrict__ a_bih, const float* __restrict__ a_bhh,
    const float* __restrict__ xtext, const float* __restrict__ xattn,
    const float* __restrict__ htT,  const float* __restrict__ haT,
    float* __restrict__ htnT, u16* __restrict__ xrib)
{
  const int tid = threadIdx.x, w = tid >> 6, lane = tid & 63;
  const int isA = blockIdx.x >= 256;
  const int d = blockIdx.x & 255;
  const float* wih = isA ? a_wih : t_wih;
  const float* whh = isA ? a_whh : t_whh;
  const float* xT  = isA ? xattn : xtext;
  const float* hT  = isA ? haT   : htT;
  __shared__ float red[8][6][64];
  float s0=0.f,s1=0.f,s2=0.f,s3=0.f,s4=0.f,s5=0.f;
  {
    const float* wr = wih + (size_t)d*384       + w*48;
    const float* wz = wih + (size_t)(256+d)*384 + w*48;
    const float* wn = wih + (size_t)(512+d)*384 + w*48;
    const float* xb = xT + w*48*64 + lane;
    #pragma unroll 4
    for (int k = 0; k < 48; k += 4){
      float4 ar = *(const float4*)(wr + k);
      float4 az = *(const float4*)(wz + k);
      float4 an = *(const float4*)(wn + k);
      float x0 = xb[(k+0)*64], x1 = xb[(k+1)*64];
      float x2 = xb[(k+2)*64], x3 = xb[(k+3)*64];
      s0 += ar.x*x0 + ar.y*x1 + ar.z*x2 + ar.w*x3;
      s1 += az.x*x0 + az.y*x1 + az.z*x2 + az.w*x3;
      s2 += an.x*x0 + an.y*x1 + an.z*x2 + an.w*x3;
    }
  }
  {
    const float* vr = whh + (size_t)d*256       + w*32;
    const float* vz = whh + (size_t)(256+d)*256 + w*32;
    const float* vn = whh + (size_t)(512+d)*256 + w*32;
    const float* hb = hT + w*32*64 + lane;
    #pragma unroll 4
    for (int k = 0; k < 32; k += 4){
      float4 ar = *(const float4*)(vr + k);
      float4 az = *(const float4*)(vz + k);
      float4 an = *(const float4*)(vn + k);
      float h0 = hb[(k+0)*64], h1 = hb[(k+1)*64];
      float h2 = hb[(k+2)*64], h3 = hb[(k+3)*64];
      s3 += ar.x*h0 + ar.y*h1 + ar.z*h2 + ar.w*h3;
      s4 += az.x*h0 + az.y*h1 + az.z*h2 + az.w*h3;
      s5 += an.x*h0 + an.y*h1 + an.z*h2 + an.w*h3;
    }
  }
  red[w][0][lane]=s0; red[w][1][lane]=s1; red[w][2][lane]=s2;
  red[w][3][lane]=s3; red[w][4][lane]=s4; red[w][5][lane]=s5;
  __syncthreads();
  if (w == 0){
    const float* bih = isA ? a_bih : t_bih;
    const float* bhh = isA ? a_bhh : t_bhh;
    float g6[6];
    #pragma unroll
    for (int i = 0; i < 6; ++i){
      float a = 0.f;
      #pragma unroll
      for (int ww = 0; ww < 8; ++ww) a += red[ww][i][lane];
      g6[i] = a;
    }
    float gir = bih[d]     + g6[0];
    float giz = bih[256+d] + g6[1];
    float gin = bih[512+d] + g6[2];
    float ghr = bhh[d]     + g6[3];
    float ghz = bhh[256+d] + g6[4];
    float ghn = bhh[512+d] + g6[5];
    float hd = hT[d*64 + lane];
    float r  = sigmf(gir + ghr), z = sigmf(giz + ghz);
    float nn = tanhf_fast(gin + r*ghn);
    float hnew = (1.f - z)*nn + z*hd;
    if (isA) xrib[(size_t)lane*512 + 256 + d] = f2bf(hnew);
    else     htnT[(size_t)d*64 + lane]        = hnew;
  }
}

// F4: qp. 256 blocks (block = d), 4-wave k-split + reduce.
__global__ __launch_bounds__(256) void k_qp(
    const float* __restrict__ tWm, const float* __restrict__ htnT,
    float* __restrict__ qp)
{
  const int tid = threadIdx.x, w = tid >> 6, lane = tid & 63;
  const int d = blockIdx.x;
  __shared__ float red[4][64];
  float acc = 0.f;
  const float* wr = tWm + (size_t)d*256 + w*64;
  const float* xb = htnT + w*64*64 + lane;
  #pragma unroll
  for (int k = 0; k < 64; k += 4){
    float4 wv = *(const float4*)(wr + k);
    acc += wv.x*xb[(k+0)*64] + wv.y*xb[(k+1)*64]
         + wv.z*xb[(k+2)*64] + wv.w*xb[(k+3)*64];
  }
  red[w][lane] = acc;
  __syncthreads();
  if (w == 0)
    qp[lane*ND + d] = red[0][lane]+red[1][lane]+red[2][lane]+red[3][lane];
}

// ---------------------------------------------------------------------------
// K2: attention partial pass (single read of enc).
// Fast scoring: sum v*tanh(e+q) = VS - sum 2v/(exp(2(e+q))+1).
// ---------------------------------------------------------------------------
__global__ __launch_bounds__(256) void k_attn_part(
    const float* __restrict__ enc, const float* __restrict__ qp,
    const float* __restrict__ tv,  float* __restrict__ attnP)
{
  const int tid = threadIdx.x, b = blockIdx.x, ch = blockIdx.y;
  const int wave = tid >> 6, lane = tid & 63;
  const float C2  = 2.885390082f;      // 2*log2(e)
  const float L2E = 1.4426950408f;     // log2(e)
  __shared__ float qpL[256], vL[256], ctxL[4][256], sL[4];
  qpL[tid] = qp[b*ND + tid] * C2;
  vL[tid]  = tv[tid] * 2.f;
  __syncthreads();

  const float q0 = qpL[lane*4+0], q1 = qpL[lane*4+1], q2 = qpL[lane*4+2], q3 = qpL[lane*4+3];
  const float v0 = vL[lane*4+0],  v1 = vL[lane*4+1],  v2 = vL[lane*4+2],  v3 = vL[lane*4+3];
  float vs = 0.5f*(v0 + v1 + v2 + v3);
  #pragma unroll
  for (int off = 1; off < 64; off <<= 1) vs += __shfl_xor(vs, off);
  const float VS = vs;

  float cx0=0.f, cx1=0.f, cx2=0.f, cx3=0.f, sacc=0.f;
  const float* base = enc + ((size_t)b*NTX + (size_t)ch*128 + wave*32)*ND + lane*4;
  #pragma unroll 4
  for (int i = 0; i < 32; ++i){
    float4 ev = *(const float4*)(base + (size_t)i*ND);
    float e0 = ev.x, e1 = ev.y, e2 = ev.z, e3 = ev.w;
    float srow;
    {
      float u0 = EXP2F(__builtin_fmaf(e0, C2, q0));
      float u1 = EXP2F(__builtin_fmaf(e1, C2, q1));
      float u2 = EXP2F(__builtin_fmaf(e2, C2, q2));
      float u3 = EXP2F(__builtin_fmaf(e3, C2, q3));
      srow = v0*RCPF(u0 + 1.f) + v1*RCPF(u1 + 1.f)
           + v2*RCPF(u2 + 1.f) + v3*RCPF(u3 + 1.f);
    }
    #pragma unroll
    for (int off = 1; off < 64; off <<= 1) srow += __shfl_xor(srow, off);
    float w = EXP2F((VS - srow) * L2E);
    sacc += w;
    cx0 = __builtin_fmaf(w, e0, cx0); cx1 = __builtin_fmaf(w, e1, cx1);
    cx2 = __builtin_fmaf(w, e2, cx2); cx3 = __builtin_fmaf(w, e3, cx3);
  }
  ctxL[wave][lane*4+0]=cx0; ctxL[wave][lane*4+1]=cx1;
  ctxL[wave][lane*4+2]=cx2; ctxL[wave][lane*4+3]=cx3;
  if (lane == 0) sL[wave] = sacc;
  __syncthreads();
  float c = ctxL[0][tid]+ctxL[1][tid]+ctxL[2][tid]+ctxL[3][tid];
  float* dst = attnP + ((size_t)b*16 + ch)*257;
  dst[tid] = c;
  if (tid == 0) dst[256] = sL[0]+sL[1]+sL[2]+sL[3];
}

// ---------------------------------------------------------------------------
// mm_ri + folded attn reduce: 64 blocks x 512 threads.
// Phase 1: reduce 16 attnP partials -> xctxb[64][256] bf16 in LDS (coalesced).
// Phase 2: 8 waves k-split MFMA: w<4 A-from-LDS (ctx k 0..255),
//          w>=4 A-from-global xrib rows 256.. (gru part, k 256..511).
// Phase 3: Rs reduce (rotate-swizzled), bias, write x0/x0b.
// ---------------------------------------------------------------------------
__global__ __launch_bounds__(512) void k_mm_ri(
    const float* __restrict__ attnP, const u16* __restrict__ xrib,
    const float* __restrict__ ri_w,  const float* __restrict__ ri_b,
    float* __restrict__ x0, u16* __restrict__ x0b)
{
  __shared__ u16   xctxb[64*256];     // 32 KB
  __shared__ float Rs[8*1024];        // 32 KB
  const int tid = threadIdx.x, lane = tid & 63, w = tid >> 6;
  const int n0 = blockIdx.x * 16;

  float* sInv = Rs;                   // overlap: Rs unused during phase 1
  if (tid < 64){
    float s = 0.f;
    #pragma unroll
    for (int c2 = 0; c2 < 16; ++c2) s += attnP[(size_t)(tid*16+c2)*257 + 256];
    sInv[tid] = RCPF(s);
  }
  __syncthreads();
  for (int bb = (tid >> 8); bb < 64; bb += 2){
    const int c = tid & 255;
    float v = 0.f;
    #pragma unroll
    for (int c2 = 0; c2 < 16; ++c2) v += attnP[(size_t)(bb*16+c2)*257 + c];
    xctxb[bb*256 + c] = f2bf(v * sInv[bb]);
  }
  __syncthreads();

  f32x4 acc[4];
  #pragma unroll
  for (int i = 0; i < 4; ++i) acc[i] = (f32x4){0.f,0.f,0.f,0.f};
  const int kbase = w*64;
  const float* wr = ri_w + (size_t)(n0 + (lane & 15))*512 + kbase + (lane >> 4)*8;
  #pragma unroll
  for (int t = 0; t < 2; ++t){
    float4 wa = *(const float4*)(wr + t*32);
    float4 wb = *(const float4*)(wr + t*32 + 4);
    union { bf16x8 v; uint4 u; } bf;
    bf.u.x = pk2(wa.x,wa.y); bf.u.y = pk2(wa.z,wa.w);
    bf.u.z = pk2(wb.x,wb.y); bf.u.w = pk2(wb.z,wb.w);
    #pragma unroll
    for (int fb = 0; fb < 4; ++fb){
      union { bf16x8 v; uint4 u; } af;
      const int row = fb*16 + (lane & 15);
      if (w < 4)
        af.u = *(const uint4*)(xctxb + row*256 + kbase + (lane >> 4)*8 + t*32);
      else
        af.u = *(const uint4*)(xrib + (size_t)row*512 + kbase + (lane >> 4)*8 + t*32);
      acc[fb] = __builtin_amdgcn_mfma_f32_16x16x32_bf16(af.v, bf.v, acc[fb], 0, 0, 0);
    }
  }
  __syncthreads();   // sInv/Rs overlap: ensure phase-1 reads done before Rs writes
  #pragma unroll
  for (int fb = 0; fb < 4; ++fb)
    #pragma unroll
    for (int r = 0; r < 4; ++r)
      Rs[w*1024 + fb*256 + r*64 + ((lane + w*4) & 63)] = acc[fb][r];
  __syncthreads();
  if (tid < 256){
    const int b = tid >> 2, c4 = (tid & 3)*4;
    const int fb = b >> 4, q = (b >> 2) & 3, reg = b & 3;
    #pragma unroll
    for (int cc = 0; cc < 4; ++cc){
      const int c = c4 + cc;
      const int li = q*16 + c;
      float v = ri_b[n0 + c];
      #pragma unroll
      for (int ww = 0; ww < 8; ++ww)
        v += Rs[ww*1024 + fb*256 + reg*64 + ((li + ww*4) & 63)];
      x0[(size_t)b*1024 + n0 + c]  = v;
      x0b[(size_t)b*1024 + n0 + c] = f2bf(v);
    }
  }
}

// ---------------------------------------------------------------------------
// Fused LSTM layer: 256 blocks x 1024 threads (16 waves). Block = 4 j-cols;
// 16 MFMA rows = 4 gates x 4 j. Waves 0..7: ih K-chunks of 128; 8..15: hh.
// LDS reduce, then same block applies cell + residual.
// ---------------------------------------------------------------------------
__global__ __launch_bounds__(1024) void k_lstm(
    const float* __restrict__ Wih, const float* __restrict__ Whh,
    const u16* __restrict__ xb, const u16* __restrict__ hb,
    const float* __restrict__ bih, const float* __restrict__ bhh,
    const float* __restrict__ c_in,
    const float* __restrict__ xin, float* __restrict__ xout,
    u16* __restrict__ xoutb)
{
  __shared__ float Rs[16][4][4][65];
  const int tid = threadIdx.x, lane = tid & 63, w = tid >> 6;
  const int j0 = blockIdx.x * 4;
  const float* W = (w < 8) ? Wih : Whh;
  const u16*   X = (w < 8) ? xb  : hb;
  const int kbase = (w & 7) * 128;

  f32x4 acc[4];
  #pragma unroll
  for (int i = 0; i < 4; ++i) acc[i] = (f32x4){0.f,0.f,0.f,0.f};
  const int r16 = lane & 15;
  const int g = r16 >> 2, jq = r16 & 3;
  const float* wr = W + (size_t)(g*1024 + j0 + jq)*1024 + kbase + (lane >> 4)*8;
  #pragma unroll
  for (int t = 0; t < 4; ++t){
    float4 wa = *(const float4*)(wr + t*32);
    float4 wb = *(const float4*)(wr + t*32 + 4);
    union { bf16x8 v; uint4 u; } bf;
    bf.u.x = pk2(wa.x,wa.y); bf.u.y = pk2(wa.z,wa.w);
    bf.u.z = pk2(wb.x,wb.y); bf.u.w = pk2(wb.z,wb.w);
    #pragma unroll
    for (int fb = 0; fb < 4; ++fb){
      union { bf16x8 v; uint4 u; } af;
      af.u = *(const uint4*)(X + (size_t)(fb*16 + r16)*1024 + kbase + (lane >> 4)*8 + t*32);
      acc[fb] = __builtin_amdgcn_mfma_f32_16x16x32_bf16(af.v, bf.v, acc[fb], 0, 0, 0);
    }
  }
  #pragma unroll
  for (int fb = 0; fb < 4; ++fb)
    #pragma unroll
    for (int r = 0; r < 4; ++r) Rs[w][fb][r][lane] = acc[fb][r];
  __syncthreads();

  if (tid < 256){
    const int b  = tid >> 2, jq2 = tid & 3;
    const int j  = j0 + jq2;
    const int fb = b >> 4, q = (b >> 2) & 3, reg = b & 3;
    float gate[4];
    #pragma unroll
    for (int gg = 0; gg < 4; ++gg){
      const int li = q*16 + gg*4 + jq2;
      float a = bih[gg*1024 + j] + bhh[gg*1024 + j];
      #pragma unroll
      for (int ww = 0; ww < 16; ++ww) a += Rs[ww][fb][reg][li];
      gate[gg] = a;
    }
    float ii = sigmf(gate[0]), ff = sigmf(gate[1]);
    float gv = tanhf_fast(gate[2]), oo = sigmf(gate[3]);
    float cc = ff * c_in[(size_t)b*1024 + j] + ii * gv;
    float hh = oo * tanhf_fast(cc);
    float xo = xin[(size_t)b*1024 + j] + hh;
    xout[(size_t)b*1024 + j]  = xo;
    xoutb[(size_t)b*1024 + j] = f2bf(xo);
  }
}

// K7: mel projection — only rows with col%20 < 2 of mp_w are needed.
__global__ __launch_bounds__(256) void k_mels(
    const float* __restrict__ x2, const float* __restrict__ mp_w,
    float* __restrict__ out)
{
  const int tid = threadIdx.x, b = blockIdx.x;
  __shared__ float xL[NL];
  #pragma unroll
  for (int i = 0; i < 4; ++i){
    int j = tid + 256*i;
    xL[j] = x2[(size_t)b*NL + j];
  }
  __syncthreads();
  if (tid < 160){
    int m = tid >> 1, r = tid & 1;
    float acc = dot_rowf(mp_w + (size_t)(m*20 + r)*NL, xL, 256);
    out[b*160 + tid] = acc;
  }
}

// ---------------------------------------------------------------------------
extern "C" void kernel_launch(void* const* d_in, const int* in_sizes, int n_in,
                              void* d_out, int out_size, void* d_ws, size_t ws_size,
                              hipStream_t stream)
{
  (void)in_sizes; (void)n_in; (void)out_size; (void)ws_size;
  const float* enc     = (const float*)d_in[0];
  const float* pre_in  = (const float*)d_in[2];
  const float* h_text  = (const float*)d_in[3];
  const float* h_attn  = (const float*)d_in[5];
  const float* h_r1    = (const float*)d_in[6];
  const float* h_r2    = (const float*)d_in[7];
  const float* c_r1    = (const float*)d_in[8];
  const float* c_r2    = (const float*)d_in[9];
  const float* cv_text = (const float*)d_in[10];
  const float* cv      = (const float*)d_in[12];
  const float* fc1_w   = (const float*)d_in[13];
  const float* fc1_b   = (const float*)d_in[14];
  const float* fc2_w   = (const float*)d_in[15];
  const float* fc2_b   = (const float*)d_in[16];
  const float* tWm     = (const float*)d_in[17];
  const float* tv      = (const float*)d_in[18];
  const float* t_wih   = (const float*)d_in[21];
  const float* t_whh   = (const float*)d_in[22];
  const float* t_bih   = (const float*)d_in[23];
  const float* t_bhh   = (const float*)d_in[24];
  const float* a_wih   = (const float*)d_in[29];
  const float* a_whh   = (const float*)d_in[30];
  const float* a_bih   = (const float*)d_in[31];
  const float* a_bhh   = (const float*)d_in[32];
  const float* ri_w    = (const float*)d_in[33];
  const float* ri_b    = (const float*)d_in[34];
  const float* l1_wih  = (const float*)d_in[35];
  const float* l1_whh  = (const float*)d_in[36];
  const float* l1_bih  = (const float*)d_in[37];
  const float* l1_bhh  = (const float*)d_in[38];
  const float* l2_wih  = (const float*)d_in[39];
  const float* l2_whh  = (const float*)d_in[40];
  const float* l2_bih  = (const float*)d_in[41];
  const float* l2_bhh  = (const float*)d_in[42];
  const float* mp_w    = (const float*)d_in[43];

  // workspace layout (float units, 16B-aligned regions), ~6 MB
  float* ws    = (float*)d_ws;
  float* qp    = ws;                    // 16384
  float* attnP = qp    + 16384;         // 64*16*257 = 263168
  float* x0    = attnP + 263168;        // 65536
  float* x1    = x0    + 65536;
  float* x2    = x1    + 65536;
  float* xtext = x2    + 65536;         // 24576
  float* xattn = xtext + 24576;         // 24576
  float* htT   = xattn + 24576;         // 16384
  float* haT   = htT   + 16384;
  float* htnT  = haT   + 16384;
  float* p1T   = htnT  + 16384;         // 16384
  u16*   hb1   = (u16*)(p1T + 16384);   // 65536 u16
  u16*   hb2   = hb1 + 65536;
  u16*   xrib  = hb2 + 65536;           // 64*512 (only cols 256.. used now)
  u16*   x0b   = xrib + 32768;          // 64*1024
  u16*   x1b   = x0b + 65536;
  u16*   x2b   = x1b + 65536;           // written, unused

  k_pre1<<<144, 256, 0, stream>>>(cv_text, cv, h_text, h_attn,
      pre_in, fc1_w, fc1_b, h_r1, h_r2,
      xtext, xattn, htT, haT, p1T, hb1, hb2);
  k_pre2<<<128, 256, 0, stream>>>(p1T, fc2_w, fc2_b, xtext, xattn);
  k_gru<<<512, 512, 0, stream>>>(t_wih, t_whh, t_bih, t_bhh,
      a_wih, a_whh, a_bih, a_bhh, xtext, xattn, htT, haT, htnT, xrib);
  k_qp<<<256, 256, 0, stream>>>(tWm, htnT, qp);

  k_attn_part<<<dim3(64,16), 256, 0, stream>>>(enc, qp, tv, attnP);

  k_mm_ri<<<64, 512, 0, stream>>>(attnP, xrib, ri_w, ri_b, x0, x0b);

  k_lstm<<<256, 1024, 0, stream>>>(l1_wih, l1_whh, x0b, hb1,
      l1_bih, l1_bhh, c_r1, x0, x1, x1b);
  k_lstm<<<256, 1024, 0, stream>>>(l2_wih, l2_whh, x1b, hb2,
      l2_bih, l2_bhh, c_r2, x1, x2, x2b);

  k_mels<<<64, 256, 0, stream>>>(x2, mp_w, (float*)d_out);
}

// Round 14
// 117.148 us; speedup vs baseline: 3.3484x; 1.0625x over previous
//
#include <hip/hip_runtime.h>
#include <hip/hip_bf16.h>

typedef unsigned short u16;
typedef unsigned int   u32;
typedef __attribute__((ext_vector_type(8))) short bf16x8;
typedef __attribute__((ext_vector_type(4))) float f32x4;

#define NB   64
#define NTX  2048
#define ND   256
#define NL   1024

#if __has_builtin(__builtin_amdgcn_exp2f)
#define EXP2F(x) __builtin_amdgcn_exp2f(x)
#else
#define EXP2F(x) exp2f(x)
#endif
#if __has_builtin(__builtin_amdgcn_rcpf)
#define RCPF(x) __builtin_amdgcn_rcpf(x)
#else
#define RCPF(x) (1.0f/(x))
#endif

__device__ __forceinline__ u16 f2bf(float f){
  union { float f; u32 u; } c; c.f = f;
  return (u16)((c.u + 0x7fffu + ((c.u >> 16) & 1u)) >> 16);
}
__device__ __forceinline__ u32 pk2(float a, float b){
  return (u32)f2bf(a) | ((u32)f2bf(b) << 16);
}
__device__ __forceinline__ float sigmf(float x){ return 1.f/(1.f+__expf(-x)); }
__device__ __forceinline__ float tanhf_fast(float x){
  x = fminf(fmaxf(x, -15.f), 15.f);
  float e = __expf(2.f*x);
  return (e - 1.f) / (e + 1.f);
}
__device__ __forceinline__ float dot_rowf(const float* __restrict__ row,
                                          const float* __restrict__ x, int K4){
  float acc = 0.f;
  for (int j = 0; j < K4; ++j){
    float4 w = *(const float4*)(row + j*4);
    const float* xp = x + j*4;
    acc += w.x*xp[0] + w.y*xp[1] + w.z*xp[2] + w.w*xp[3];
  }
  return acc;
}

// ---------------------------------------------------------------------------
// F1: blocks 0..15  : transposes [64][256] -> [256][64]
//     blocks 16..79 : fc1 batch-on-lanes -> p1T [256][64]
//     blocks 80..143: h_r1/h_r2 fp32 -> bf16 copies
// ---------------------------------------------------------------------------
__global__ __launch_bounds__(256) void k_pre1(
    const float* __restrict__ cv_text, const float* __restrict__ cv,
    const float* __restrict__ h_text,  const float* __restrict__ h_attn,
    const float* __restrict__ prenet_in,
    const float* __restrict__ fc1_w, const float* __restrict__ fc1_b,
    const float* __restrict__ h_r1, const float* __restrict__ h_r2,
    float* __restrict__ xtext, float* __restrict__ xattn,
    float* __restrict__ htT,  float* __restrict__ haT,
    float* __restrict__ p1T,
    u16* __restrict__ hb1, u16* __restrict__ hb2)
{
  __shared__ float ld[64][65];
  const int blk = blockIdx.x, tid = threadIdx.x;
  if (blk < 16){
    int a = blk >> 2; int c0 = (blk & 3)*64;
    const float* src = (a==0)?cv_text:(a==1)?cv:(a==2)?h_text:h_attn;
    float* dst = (a==0)?xtext:(a==1)?xattn:(a==2)?htT:haT;
    const int r = tid >> 2, q = tid & 3;
    #pragma unroll
    for (int i = 0; i < 4; ++i){
      float4 v = *(const float4*)(src + (size_t)r*256 + c0 + q*16 + i*4);
      ld[r][q*16+i*4+0] = v.x; ld[r][q*16+i*4+1] = v.y;
      ld[r][q*16+i*4+2] = v.z; ld[r][q*16+i*4+3] = v.w;
    }
    __syncthreads();
    const int cc = tid >> 2;
    #pragma unroll
    for (int i = 0; i < 4; ++i){
      int b0 = q*16 + i*4;
      float4 o = { ld[b0+0][cc], ld[b0+1][cc], ld[b0+2][cc], ld[b0+3][cc] };
      *(float4*)(dst + (size_t)(c0+cc)*64 + b0) = o;
    }
  } else if (blk < 80){
    const int wave = tid >> 6, lane = tid & 63;
    const int n = (blk - 16)*4 + wave;
    float acc = fc1_b[n];
    const float* wr = fc1_w + (size_t)n*80;
    const float* xr = prenet_in + (size_t)lane*80;
    #pragma unroll
    for (int k = 0; k < 80; k += 4){
      float4 w = *(const float4*)(wr + k);
      acc += w.x*xr[k] + w.y*xr[k+1] + w.z*xr[k+2] + w.w*xr[k+3];
    }
    p1T[n*64 + lane] = fmaxf(acc, 0.f);
  } else {
    const int t2 = blk - 80;
    const float* src = (t2 < 32) ? h_r1 : h_r2;
    u16* dst = (t2 < 32) ? hb1 : hb2;
    const int base = (t2 & 31)*2048 + tid*8;
    float4 a = *(const float4*)(src + base);
    float4 b = *(const float4*)(src + base + 4);
    uint4 o = { pk2(a.x,a.y), pk2(a.z,a.w), pk2(b.x,b.y), pk2(b.z,b.w) };
    *(uint4*)(dst + base) = o;
  }
}

// F2: fc2, 128 blocks (block = n), 4-wave k-split + LDS reduce.
__global__ __launch_bounds__(256) void k_pre2(
    const float* __restrict__ p1T,
    const float* __restrict__ fc2_w, const float* __restrict__ fc2_b,
    float* __restrict__ xtext, float* __restrict__ xattn)
{
  const int tid = threadIdx.x, w = tid >> 6, lane = tid & 63;
  const int n = blockIdx.x;
  __shared__ float red[4][64];
  float acc = 0.f;
  const float* wr = fc2_w + (size_t)n*256 + w*64;
  const float* xb = p1T + w*64*64 + lane;
  #pragma unroll
  for (int k = 0; k < 64; k += 4){
    float4 wv = *(const float4*)(wr + k);
    acc += wv.x*xb[(k+0)*64] + wv.y*xb[(k+1)*64]
         + wv.z*xb[(k+2)*64] + wv.w*xb[(k+3)*64];
  }
  red[w][lane] = acc;
  __syncthreads();
  if (w == 0){
    float v = fmaxf(red[0][lane]+red[1][lane]+red[2][lane]+red[3][lane] + fc2_b[n], 0.f);
    xtext[(size_t)(256+n)*64 + lane] = v;
    xattn[(size_t)(256+n)*64 + lane] = v;
  }
}

// F3: GRUs. 512 blocks x 512 threads (8 waves k-split + LDS reduce).
__global__ __launch_bounds__(512) void k_gru(
    const float* __restrict__ t_wih, const float* __restrict__ t_whh,
    const float* __restrict__ t_bih, const float* __restrict__ t_bhh,
    const float* __restrict__ a_wih, const float* __restrict__ a_whh,
    const float* __restrict__ a_bih, const float* __restrict__ a_bhh,
    const float* __restrict__ xtext, const float* __restrict__ xattn,
    const float* __restrict__ htT,  const float* __restrict__ haT,
    float* __restrict__ htnT, u16* __restrict__ xrib)
{
  const int tid = threadIdx.x, w = tid >> 6, lane = tid & 63;
  const int isA = blockIdx.x >= 256;
  const int d = blockIdx.x & 255;
  const float* wih = isA ? a_wih : t_wih;
  const float* whh = isA ? a_whh : t_whh;
  const float* xT  = isA ? xattn : xtext;
  const float* hT  = isA ? haT   : htT;
  __shared__ float red[8][6][64];
  float s0=0.f,s1=0.f,s2=0.f,s3=0.f,s4=0.f,s5=0.f;
  {
    const float* wr = wih + (size_t)d*384       + w*48;
    const float* wz = wih + (size_t)(256+d)*384 + w*48;
    const float* wn = wih + (size_t)(512+d)*384 + w*48;
    const float* xb = xT + w*48*64 + lane;
    #pragma unroll 4
    for (int k = 0; k < 48; k += 4){
      float4 ar = *(const float4*)(wr + k);
      float4 az = *(const float4*)(wz + k);
      float4 an = *(const float4*)(wn + k);
      float x0 = xb[(k+0)*64], x1 = xb[(k+1)*64];
      float x2 = xb[(k+2)*64], x3 = xb[(k+3)*64];
      s0 += ar.x*x0 + ar.y*x1 + ar.z*x2 + ar.w*x3;
      s1 += az.x*x0 + az.y*x1 + az.z*x2 + az.w*x3;
      s2 += an.x*x0 + an.y*x1 + an.z*x2 + an.w*x3;
    }
  }
  {
    const float* vr = whh + (size_t)d*256       + w*32;
    const float* vz = whh + (size_t)(256+d)*256 + w*32;
    const float* vn = whh + (size_t)(512+d)*256 + w*32;
    const float* hb = hT + w*32*64 + lane;
    #pragma unroll 4
    for (int k = 0; k < 32; k += 4){
      float4 ar = *(const float4*)(vr + k);
      float4 az = *(const float4*)(vz + k);
      float4 an = *(const float4*)(vn + k);
      float h0 = hb[(k+0)*64], h1 = hb[(k+1)*64];
      float h2 = hb[(k+2)*64], h3 = hb[(k+3)*64];
      s3 += ar.x*h0 + ar.y*h1 + ar.z*h2 + ar.w*h3;
      s4 += az.x*h0 + az.y*h1 + az.z*h2 + az.w*h3;
      s5 += an.x*h0 + an.y*h1 + an.z*h2 + an.w*h3;
    }
  }
  red[w][0][lane]=s0; red[w][1][lane]=s1; red[w][2][lane]=s2;
  red[w][3][lane]=s3; red[w][4][lane]=s4; red[w][5][lane]=s5;
  __syncthreads();
  if (w == 0){
    const float* bih = isA ? a_bih : t_bih;
    const float* bhh = isA ? a_bhh : t_bhh;
    float g6[6];
    #pragma unroll
    for (int i = 0; i < 6; ++i){
      float a = 0.f;
      #pragma unroll
      for (int ww = 0; ww < 8; ++ww) a += red[ww][i][lane];
      g6[i] = a;
    }
    float gir = bih[d]     + g6[0];
    float giz = bih[256+d] + g6[1];
    float gin = bih[512+d] + g6[2];
    float ghr = bhh[d]     + g6[3];
    float ghz = bhh[256+d] + g6[4];
    float ghn = bhh[512+d] + g6[5];
    float hd = hT[d*64 + lane];
    float r  = sigmf(gir + ghr), z = sigmf(giz + ghz);
    float nn = tanhf_fast(gin + r*ghn);
    float hnew = (1.f - z)*nn + z*hd;
    if (isA) xrib[(size_t)lane*512 + 256 + d] = f2bf(hnew);
    else     htnT[(size_t)d*64 + lane]        = hnew;
  }
}

// F4: qp. 256 blocks (block = d), 4-wave k-split + reduce.
__global__ __launch_bounds__(256) void k_qp(
    const float* __restrict__ tWm, const float* __restrict__ htnT,
    float* __restrict__ qp)
{
  const int tid = threadIdx.x, w = tid >> 6, lane = tid & 63;
  const int d = blockIdx.x;
  __shared__ float red[4][64];
  float acc = 0.f;
  const float* wr = tWm + (size_t)d*256 + w*64;
  const float* xb = htnT + w*64*64 + lane;
  #pragma unroll
  for (int k = 0; k < 64; k += 4){
    float4 wv = *(const float4*)(wr + k);
    acc += wv.x*xb[(k+0)*64] + wv.y*xb[(k+1)*64]
         + wv.z*xb[(k+2)*64] + wv.w*xb[(k+3)*64];
  }
  red[w][lane] = acc;
  __syncthreads();
  if (w == 0)
    qp[lane*ND + d] = red[0][lane]+red[1][lane]+red[2][lane]+red[3][lane];
}

// ---------------------------------------------------------------------------
// K2: attention partial pass. Grid (64 b, 32 chunks of 64 t), 256 thr.
// 2048 blocks -> 8 blocks/CU (32 waves/CU). Each wave: 16 rows as 8
// row-PAIRS (2 independent loads + 2 interleaved score chains per iter).
// ---------------------------------------------------------------------------
__global__ __launch_bounds__(256) void k_attn_part(
    const float* __restrict__ enc, const float* __restrict__ qp,
    const float* __restrict__ tv,  float* __restrict__ attnP)
{
  const int tid = threadIdx.x, b = blockIdx.x, ch = blockIdx.y;
  const int wave = tid >> 6, lane = tid & 63;
  const float C2  = 2.885390082f;      // 2*log2(e)
  const float L2E = 1.4426950408f;     // log2(e)
  __shared__ float qpL[256], vL[256], ctxL[4][256], sL[4];
  qpL[tid] = qp[b*ND + tid] * C2;
  vL[tid]  = tv[tid] * 2.f;
  __syncthreads();

  const float q0 = qpL[lane*4+0], q1 = qpL[lane*4+1], q2 = qpL[lane*4+2], q3 = qpL[lane*4+3];
  const float v0 = vL[lane*4+0],  v1 = vL[lane*4+1],  v2 = vL[lane*4+2],  v3 = vL[lane*4+3];
  float vs = 0.5f*(v0 + v1 + v2 + v3);
  #pragma unroll
  for (int off = 1; off < 64; off <<= 1) vs += __shfl_xor(vs, off);
  const float VS = vs;

  float cx0=0.f, cx1=0.f, cx2=0.f, cx3=0.f, sacc=0.f;
  // wave covers rows [ch*64 + wave*16, +16), as pairs (i, i+8)
  const float* base = enc + ((size_t)b*NTX + (size_t)ch*64 + wave*16)*ND + lane*4;
  #pragma unroll 2
  for (int i = 0; i < 8; ++i){
    float4 evA = *(const float4*)(base + (size_t)i*ND);
    float4 evB = *(const float4*)(base + (size_t)(i+8)*ND);
    float uA0 = EXP2F(__builtin_fmaf(evA.x, C2, q0));
    float uB0 = EXP2F(__builtin_fmaf(evB.x, C2, q0));
    float uA1 = EXP2F(__builtin_fmaf(evA.y, C2, q1));
    float uB1 = EXP2F(__builtin_fmaf(evB.y, C2, q1));
    float uA2 = EXP2F(__builtin_fmaf(evA.z, C2, q2));
    float uB2 = EXP2F(__builtin_fmaf(evB.z, C2, q2));
    float uA3 = EXP2F(__builtin_fmaf(evA.w, C2, q3));
    float uB3 = EXP2F(__builtin_fmaf(evB.w, C2, q3));
    float srowA = v0*RCPF(uA0 + 1.f) + v1*RCPF(uA1 + 1.f)
                + v2*RCPF(uA2 + 1.f) + v3*RCPF(uA3 + 1.f);
    float srowB = v0*RCPF(uB0 + 1.f) + v1*RCPF(uB1 + 1.f)
                + v2*RCPF(uB2 + 1.f) + v3*RCPF(uB3 + 1.f);
    #pragma unroll
    for (int off = 1; off < 64; off <<= 1){
      srowA += __shfl_xor(srowA, off);
      srowB += __shfl_xor(srowB, off);
    }
    float wA = EXP2F((VS - srowA) * L2E);
    float wB = EXP2F((VS - srowB) * L2E);
    sacc += wA + wB;
    cx0 = __builtin_fmaf(wA, evA.x, cx0); cx0 = __builtin_fmaf(wB, evB.x, cx0);
    cx1 = __builtin_fmaf(wA, evA.y, cx1); cx1 = __builtin_fmaf(wB, evB.y, cx1);
    cx2 = __builtin_fmaf(wA, evA.z, cx2); cx2 = __builtin_fmaf(wB, evB.z, cx2);
    cx3 = __builtin_fmaf(wA, evA.w, cx3); cx3 = __builtin_fmaf(wB, evB.w, cx3);
  }
  ctxL[wave][lane*4+0]=cx0; ctxL[wave][lane*4+1]=cx1;
  ctxL[wave][lane*4+2]=cx2; ctxL[wave][lane*4+3]=cx3;
  if (lane == 0) sL[wave] = sacc;
  __syncthreads();
  float c = ctxL[0][tid]+ctxL[1][tid]+ctxL[2][tid]+ctxL[3][tid];
  float* dst = attnP + ((size_t)b*32 + ch)*257;
  dst[tid] = c;
  if (tid == 0) dst[256] = sL[0]+sL[1]+sL[2]+sL[3];
}

// K3: combine 32 chunk partials -> xrib rows 0..255 (bf16)
__global__ __launch_bounds__(256) void k_attn_red(
    const float* __restrict__ attnP, u16* __restrict__ xrib)
{
  const int tid = threadIdx.x, b = blockIdx.x;
  float c = 0.f, s = 0.f;
  for (int ch = 0; ch < 32; ++ch){
    const float* src = attnP + ((size_t)b*32 + ch)*257;
    c += src[tid]; s += src[256];
  }
  xrib[(size_t)b*512 + tid] = f2bf(c / s);
}

// ---------------------------------------------------------------------------
// MFMA GEMMs (A direct from global bf16, no LDS staging).
// D[b][col]: b = fb*16+(lane>>4)*4+reg, col = lane&15.
// ---------------------------------------------------------------------------

// ri projection: 64 blocks x 512 threads; 8 waves k-split (64 each).
__global__ __launch_bounds__(512) void k_mm_ri(
    const u16* __restrict__ xrib, const float* __restrict__ ri_w,
    const float* __restrict__ ri_b, float* __restrict__ x0,
    u16* __restrict__ x0b)
{
  __shared__ float Rs[8][4][4][65];
  const int tid = threadIdx.x, lane = tid & 63, w = tid >> 6;
  const int n0 = blockIdx.x * 16;
  f32x4 acc[4];
  #pragma unroll
  for (int i = 0; i < 4; ++i) acc[i] = (f32x4){0.f,0.f,0.f,0.f};
  const int kbase = w*64;
  const float* wr = ri_w + (size_t)(n0 + (lane & 15))*512 + kbase + (lane >> 4)*8;
  const u16* xs = xrib + (size_t)(lane & 15)*512 + kbase + (lane >> 4)*8;
  #pragma unroll
  for (int t = 0; t < 2; ++t){
    float4 wa = *(const float4*)(wr + t*32);
    float4 wb = *(const float4*)(wr + t*32 + 4);
    union { bf16x8 v; uint4 u; } bf;
    bf.u.x = pk2(wa.x,wa.y); bf.u.y = pk2(wa.z,wa.w);
    bf.u.z = pk2(wb.x,wb.y); bf.u.w = pk2(wb.z,wb.w);
    #pragma unroll
    for (int fb = 0; fb < 4; ++fb){
      union { bf16x8 v; uint4 u; } af;
      af.u = *(const uint4*)(xs + fb*16*512 + t*32);
      acc[fb] = __builtin_amdgcn_mfma_f32_16x16x32_bf16(af.v, bf.v, acc[fb], 0, 0, 0);
    }
  }
  #pragma unroll
  for (int fb = 0; fb < 4; ++fb)
    #pragma unroll
    for (int r = 0; r < 4; ++r) Rs[w][fb][r][lane] = acc[fb][r];
  __syncthreads();
  if (tid < 256){
    const int b = tid >> 2, c4 = (tid & 3)*4;
    const int fb = b >> 4, q = (b >> 2) & 3, reg = b & 3;
    #pragma unroll
    for (int cc = 0; cc < 4; ++cc){
      const int c = c4 + cc;
      float v = ri_b[n0 + c];
      #pragma unroll
      for (int ww = 0; ww < 8; ++ww) v += Rs[ww][fb][reg][q*16 + c];
      x0[(size_t)b*1024 + n0 + c]  = v;
      x0b[(size_t)b*1024 + n0 + c] = f2bf(v);
    }
  }
}

// ---------------------------------------------------------------------------
// Fused LSTM layer: 256 blocks x 1024 threads (16 waves). Block = 4 j-cols;
// 16 MFMA rows = 4 gates x 4 j. Waves 0..7: ih K-chunks of 128; 8..15: hh.
// LDS reduce, then same block applies cell + residual.
// ---------------------------------------------------------------------------
__global__ __launch_bounds__(1024) void k_lstm(
    const float* __restrict__ Wih, const float* __restrict__ Whh,
    const u16* __restrict__ xb, const u16* __restrict__ hb,
    const float* __restrict__ bih, const float* __restrict__ bhh,
    const float* __restrict__ c_in,
    const float* __restrict__ xin, float* __restrict__ xout,
    u16* __restrict__ xoutb)
{
  __shared__ float Rs[16][4][4][65];
  const int tid = threadIdx.x, lane = tid & 63, w = tid >> 6;
  const int j0 = blockIdx.x * 4;
  const float* W = (w < 8) ? Wih : Whh;
  const u16*   X = (w < 8) ? xb  : hb;
  const int kbase = (w & 7) * 128;

  f32x4 acc[4];
  #pragma unroll
  for (int i = 0; i < 4; ++i) acc[i] = (f32x4){0.f,0.f,0.f,0.f};
  const int r16 = lane & 15;
  const int g = r16 >> 2, jq = r16 & 3;
  const float* wr = W + (size_t)(g*1024 + j0 + jq)*1024 + kbase + (lane >> 4)*8;
  #pragma unroll
  for (int t = 0; t < 4; ++t){
    float4 wa = *(const float4*)(wr + t*32);
    float4 wb = *(const float4*)(wr + t*32 + 4);
    union { bf16x8 v; uint4 u; } bf;
    bf.u.x = pk2(wa.x,wa.y); bf.u.y = pk2(wa.z,wa.w);
    bf.u.z = pk2(wb.x,wb.y); bf.u.w = pk2(wb.z,wb.w);
    #pragma unroll
    for (int fb = 0; fb < 4; ++fb){
      union { bf16x8 v; uint4 u; } af;
      af.u = *(const uint4*)(X + (size_t)(fb*16 + r16)*1024 + kbase + (lane >> 4)*8 + t*32);
      acc[fb] = __builtin_amdgcn_mfma_f32_16x16x32_bf16(af.v, bf.v, acc[fb], 0, 0, 0);
    }
  }
  #pragma unroll
  for (int fb = 0; fb < 4; ++fb)
    #pragma unroll
    for (int r = 0; r < 4; ++r) Rs[w][fb][r][lane] = acc[fb][r];
  __syncthreads();

  if (tid < 256){
    const int b  = tid >> 2, jq2 = tid & 3;
    const int j  = j0 + jq2;
    const int fb = b >> 4, q = (b >> 2) & 3, reg = b & 3;
    float gate[4];
    #pragma unroll
    for (int gg = 0; gg < 4; ++gg){
      const int li = q*16 + gg*4 + jq2;
      float a = bih[gg*1024 + j] + bhh[gg*1024 + j];
      #pragma unroll
      for (int ww = 0; ww < 16; ++ww) a += Rs[ww][fb][reg][li];
      gate[gg] = a;
    }
    float ii = sigmf(gate[0]), ff = sigmf(gate[1]);
    float gv = tanhf_fast(gate[2]), oo = sigmf(gate[3]);
    float cc = ff * c_in[(size_t)b*1024 + j] + ii * gv;
    float hh = oo * tanhf_fast(cc);
    float xo = xin[(size_t)b*1024 + j] + hh;
    xout[(size_t)b*1024 + j]  = xo;
    xoutb[(size_t)b*1024 + j] = f2bf(xo);
  }
}

// K7: mel projection — only rows with col%20 < 2 of mp_w are needed.
__global__ __launch_bounds__(256) void k_mels(
    const float* __restrict__ x2, const float* __restrict__ mp_w,
    float* __restrict__ out)
{
  const int tid = threadIdx.x, b = blockIdx.x;
  __shared__ float xL[NL];
  #pragma unroll
  for (int i = 0; i < 4; ++i){
    int j = tid + 256*i;
    xL[j] = x2[(size_t)b*NL + j];
  }
  __syncthreads();
  if (tid < 160){
    int m = tid >> 1, r = tid & 1;
    float acc = dot_rowf(mp_w + (size_t)(m*20 + r)*NL, xL, 256);
    out[b*160 + tid] = acc;
  }
}

// ---------------------------------------------------------------------------
extern "C" void kernel_launch(void* const* d_in, const int* in_sizes, int n_in,
                              void* d_out, int out_size, void* d_ws, size_t ws_size,
                              hipStream_t stream)
{
  (void)in_sizes; (void)n_in; (void)out_size; (void)ws_size;
  const float* enc     = (const float*)d_in[0];
  const float* pre_in  = (const float*)d_in[2];
  const float* h_text  = (const float*)d_in[3];
  const float* h_attn  = (const float*)d_in[5];
  const float* h_r1    = (const float*)d_in[6];
  const float* h_r2    = (const float*)d_in[7];
  const float* c_r1    = (const float*)d_in[8];
  const float* c_r2    = (const float*)d_in[9];
  const float* cv_text = (const float*)d_in[10];
  const float* cv      = (const float*)d_in[12];
  const float* fc1_w   = (const float*)d_in[13];
  const float* fc1_b   = (const float*)d_in[14];
  const float* fc2_w   = (const float*)d_in[15];
  const float* fc2_b   = (const float*)d_in[16];
  const float* tWm     = (const float*)d_in[17];
  const float* tv      = (const float*)d_in[18];
  const float* t_wih   = (const float*)d_in[21];
  const float* t_whh   = (const float*)d_in[22];
  const float* t_bih   = (const float*)d_in[23];
  const float* t_bhh   = (const float*)d_in[24];
  const float* a_wih   = (const float*)d_in[29];
  const float* a_whh   = (const float*)d_in[30];
  const float* a_bih   = (const float*)d_in[31];
  const float* a_bhh   = (const float*)d_in[32];
  const float* ri_w    = (const float*)d_in[33];
  const float* ri_b    = (const float*)d_in[34];
  const float* l1_wih  = (const float*)d_in[35];
  const float* l1_whh  = (const float*)d_in[36];
  const float* l1_bih  = (const float*)d_in[37];
  const float* l1_bhh  = (const float*)d_in[38];
  const float* l2_wih  = (const float*)d_in[39];
  const float* l2_whh  = (const float*)d_in[40];
  const float* l2_bih  = (const float*)d_in[41];
  const float* l2_bhh  = (const float*)d_in[42];
  const float* mp_w    = (const float*)d_in[43];

  // workspace layout (float units, 16B-aligned regions), ~7 MB
  float* ws    = (float*)d_ws;
  float* qp    = ws;                    // 16384
  float* attnP = qp    + 16384;         // 64*32*257 = 526336
  float* x0    = attnP + 526336;        // 65536
  float* x1    = x0    + 65536;
  float* x2    = x1    + 65536;
  float* xtext = x2    + 65536;         // 24576
  float* xattn = xtext + 24576;         // 24576
  float* htT   = xattn + 24576;         // 16384
  float* haT   = htT   + 16384;
  float* htnT  = haT   + 16384;
  float* p1T   = htnT  + 16384;         // 16384
  u16*   hb1   = (u16*)(p1T + 16384);   // 65536 u16
  u16*   hb2   = hb1 + 65536;
  u16*   xrib  = hb2 + 65536;           // 64*512
  u16*   x0b   = xrib + 32768;          // 64*1024
  u16*   x1b   = x0b + 65536;
  u16*   x2b   = x1b + 65536;           // written, unused

  k_pre1<<<144, 256, 0, stream>>>(cv_text, cv, h_text, h_attn,
      pre_in, fc1_w, fc1_b, h_r1, h_r2,
      xtext, xattn, htT, haT, p1T, hb1, hb2);
  k_pre2<<<128, 256, 0, stream>>>(p1T, fc2_w, fc2_b, xtext, xattn);
  k_gru<<<512, 512, 0, stream>>>(t_wih, t_whh, t_bih, t_bhh,
      a_wih, a_whh, a_bih, a_bhh, xtext, xattn, htT, haT, htnT, xrib);
  k_qp<<<256, 256, 0, stream>>>(tWm, htnT, qp);

  k_attn_part<<<dim3(64,32), 256, 0, stream>>>(enc, qp, tv, attnP);
  k_attn_red<<<64, 256, 0, stream>>>(attnP, xrib);

  k_mm_ri<<<64, 512, 0, stream>>>(xrib, ri_w, ri_b, x0, x0b);

  k_lstm<<<256, 1024, 0, stream>>>(l1_wih, l1_whh, x0b, hb1,
      l1_bih, l1_bhh, c_r1, x0, x1, x1b);
  k_lstm<<<256, 1024, 0, stream>>>(l2_wih, l2_whh, x1b, hb2,
      l2_bih, l2_bhh, c_r2, x1, x2, x2b);

  k_mels<<<64, 256, 0, stream>>>(x2, mp_w, (float*)d_out);
}

// Round 15
// 110.676 us; speedup vs baseline: 3.5442x; 1.0585x over previous
//
#include <hip/hip_runtime.h>
#include <hip/hip_bf16.h>

typedef unsigned short u16;
typedef unsigned int   u32;
typedef __attribute__((ext_vector_type(8))) short bf16x8;
typedef __attribute__((ext_vector_type(4))) float f32x4;

#define NB   64
#define NTX  2048
#define ND   256
#define NL   1024

#if __has_builtin(__builtin_amdgcn_exp2f)
#define EXP2F(x) __builtin_amdgcn_exp2f(x)
#else
#define EXP2F(x) exp2f(x)
#endif
#if __has_builtin(__builtin_amdgcn_rcpf)
#define RCPF(x) __builtin_amdgcn_rcpf(x)
#else
#define RCPF(x) (1.0f/(x))
#endif

__device__ __forceinline__ u16 f2bf(float f){
  union { float f; u32 u; } c; c.f = f;
  return (u16)((c.u + 0x7fffu + ((c.u >> 16) & 1u)) >> 16);
}
__device__ __forceinline__ u32 pk2(float a, float b){
  return (u32)f2bf(a) | ((u32)f2bf(b) << 16);
}
__device__ __forceinline__ float sigmf(float x){ return 1.f/(1.f+__expf(-x)); }
__device__ __forceinline__ float tanhf_fast(float x){
  x = fminf(fmaxf(x, -15.f), 15.f);
  float e = __expf(2.f*x);
  return (e - 1.f) / (e + 1.f);
}
__device__ __forceinline__ float dot_rowf(const float* __restrict__ row,
                                          const float* __restrict__ x, int K4){
  float acc = 0.f;
  for (int j = 0; j < K4; ++j){
    float4 w = *(const float4*)(row + j*4);
    const float* xp = x + j*4;
    acc += w.x*xp[0] + w.y*xp[1] + w.z*xp[2] + w.w*xp[3];
  }
  return acc;
}

// ---------------------------------------------------------------------------
// F1: blocks 0..15  : transposes [64][256] -> [256][64]
//     blocks 16..79 : fc1 batch-on-lanes -> p1T [256][64]
//     blocks 80..143: h_r1/h_r2 fp32 -> bf16 copies
// ---------------------------------------------------------------------------
__global__ __launch_bounds__(256) void k_pre1(
    const float* __restrict__ cv_text, const float* __restrict__ cv,
    const float* __restrict__ h_text,  const float* __restrict__ h_attn,
    const float* __restrict__ prenet_in,
    const float* __restrict__ fc1_w, const float* __restrict__ fc1_b,
    const float* __restrict__ h_r1, const float* __restrict__ h_r2,
    float* __restrict__ xtext, float* __restrict__ xattn,
    float* __restrict__ htT,  float* __restrict__ haT,
    float* __restrict__ p1T,
    u16* __restrict__ hb1, u16* __restrict__ hb2)
{
  __shared__ float ld[64][65];
  const int blk = blockIdx.x, tid = threadIdx.x;
  if (blk < 16){
    int a = blk >> 2; int c0 = (blk & 3)*64;
    const float* src = (a==0)?cv_text:(a==1)?cv:(a==2)?h_text:h_attn;
    float* dst = (a==0)?xtext:(a==1)?xattn:(a==2)?htT:haT;
    const int r = tid >> 2, q = tid & 3;
    #pragma unroll
    for (int i = 0; i < 4; ++i){
      float4 v = *(const float4*)(src + (size_t)r*256 + c0 + q*16 + i*4);
      ld[r][q*16+i*4+0] = v.x; ld[r][q*16+i*4+1] = v.y;
      ld[r][q*16+i*4+2] = v.z; ld[r][q*16+i*4+3] = v.w;
    }
    __syncthreads();
    const int cc = tid >> 2;
    #pragma unroll
    for (int i = 0; i < 4; ++i){
      int b0 = q*16 + i*4;
      float4 o = { ld[b0+0][cc], ld[b0+1][cc], ld[b0+2][cc], ld[b0+3][cc] };
      *(float4*)(dst + (size_t)(c0+cc)*64 + b0) = o;
    }
  } else if (blk < 80){
    const int wave = tid >> 6, lane = tid & 63;
    const int n = (blk - 16)*4 + wave;
    float acc = fc1_b[n];
    const float* wr = fc1_w + (size_t)n*80;
    const float* xr = prenet_in + (size_t)lane*80;
    #pragma unroll
    for (int k = 0; k < 80; k += 4){
      float4 w = *(const float4*)(wr + k);
      acc += w.x*xr[k] + w.y*xr[k+1] + w.z*xr[k+2] + w.w*xr[k+3];
    }
    p1T[n*64 + lane] = fmaxf(acc, 0.f);
  } else {
    const int t2 = blk - 80;
    const float* src = (t2 < 32) ? h_r1 : h_r2;
    u16* dst = (t2 < 32) ? hb1 : hb2;
    const int base = (t2 & 31)*2048 + tid*8;
    float4 a = *(const float4*)(src + base);
    float4 b = *(const float4*)(src + base + 4);
    uint4 o = { pk2(a.x,a.y), pk2(a.z,a.w), pk2(b.x,b.y), pk2(b.z,b.w) };
    *(uint4*)(dst + base) = o;
  }
}

// F2: fc2, 128 blocks (block = n), 4-wave k-split + LDS reduce.
__global__ __launch_bounds__(256) void k_pre2(
    const float* __restrict__ p1T,
    const float* __restrict__ fc2_w, const float* __restrict__ fc2_b,
    float* __restrict__ xtext, float* __restrict__ xattn)
{
  const int tid = threadIdx.x, w = tid >> 6, lane = tid & 63;
  const int n = blockIdx.x;
  __shared__ float red[4][64];
  float acc = 0.f;
  const float* wr = fc2_w + (size_t)n*256 + w*64;
  const float* xb = p1T + w*64*64 + lane;
  #pragma unroll
  for (int k = 0; k < 64; k += 4){
    float4 wv = *(const float4*)(wr + k);
    acc += wv.x*xb[(k+0)*64] + wv.y*xb[(k+1)*64]
         + wv.z*xb[(k+2)*64] + wv.w*xb[(k+3)*64];
  }
  red[w][lane] = acc;
  __syncthreads();
  if (w == 0){
    float v = fmaxf(red[0][lane]+red[1][lane]+red[2][lane]+red[3][lane] + fc2_b[n], 0.f);
    xtext[(size_t)(256+n)*64 + lane] = v;
    xattn[(size_t)(256+n)*64 + lane] = v;
  }
}

// F3: GRUs. 512 blocks x 512 threads (8 waves k-split + LDS reduce).
__global__ __launch_bounds__(512) void k_gru(
    const float* __restrict__ t_wih, const float* __restrict__ t_whh,
    const float* __restrict__ t_bih, const float* __restrict__ t_bhh,
    const float* __restrict__ a_wih, const float* __restrict__ a_whh,
    const float* __restrict__ a_bih, const float* __restrict__ a_bhh,
    const float* __restrict__ xtext, const float* __restrict__ xattn,
    const float* __restrict__ htT,  const float* __restrict__ haT,
    float* __restrict__ htnT, u16* __restrict__ xrib)
{
  const int tid = threadIdx.x, w = tid >> 6, lane = tid & 63;
  const int isA = blockIdx.x >= 256;
  const int d = blockIdx.x & 255;
  const float* wih = isA ? a_wih : t_wih;
  const float* whh = isA ? a_whh : t_whh;
  const float* xT  = isA ? xattn : xtext;
  const float* hT  = isA ? haT   : htT;
  __shared__ float red[8][6][64];
  float s0=0.f,s1=0.f,s2=0.f,s3=0.f,s4=0.f,s5=0.f;
  {
    const float* wr = wih + (size_t)d*384       + w*48;
    const float* wz = wih + (size_t)(256+d)*384 + w*48;
    const float* wn = wih + (size_t)(512+d)*384 + w*48;
    const float* xb = xT + w*48*64 + lane;
    #pragma unroll 4
    for (int k = 0; k < 48; k += 4){
      float4 ar = *(const float4*)(wr + k);
      float4 az = *(const float4*)(wz + k);
      float4 an = *(const float4*)(wn + k);
      float x0 = xb[(k+0)*64], x1 = xb[(k+1)*64];
      float x2 = xb[(k+2)*64], x3 = xb[(k+3)*64];
      s0 += ar.x*x0 + ar.y*x1 + ar.z*x2 + ar.w*x3;
      s1 += az.x*x0 + az.y*x1 + az.z*x2 + az.w*x3;
      s2 += an.x*x0 + an.y*x1 + an.z*x2 + an.w*x3;
    }
  }
  {
    const float* vr = whh + (size_t)d*256       + w*32;
    const float* vz = whh + (size_t)(256+d)*256 + w*32;
    const float* vn = whh + (size_t)(512+d)*256 + w*32;
    const float* hb = hT + w*32*64 + lane;
    #pragma unroll 4
    for (int k = 0; k < 32; k += 4){
      float4 ar = *(const float4*)(vr + k);
      float4 az = *(const float4*)(vz + k);
      float4 an = *(const float4*)(vn + k);
      float h0 = hb[(k+0)*64], h1 = hb[(k+1)*64];
      float h2 = hb[(k+2)*64], h3 = hb[(k+3)*64];
      s3 += ar.x*h0 + ar.y*h1 + ar.z*h2 + ar.w*h3;
      s4 += az.x*h0 + az.y*h1 + az.z*h2 + az.w*h3;
      s5 += an.x*h0 + an.y*h1 + an.z*h2 + an.w*h3;
    }
  }
  red[w][0][lane]=s0; red[w][1][lane]=s1; red[w][2][lane]=s2;
  red[w][3][lane]=s3; red[w][4][lane]=s4; red[w][5][lane]=s5;
  __syncthreads();
  if (w == 0){
    const float* bih = isA ? a_bih : t_bih;
    const float* bhh = isA ? a_bhh : t_bhh;
    float g6[6];
    #pragma unroll
    for (int i = 0; i < 6; ++i){
      float a = 0.f;
      #pragma unroll
      for (int ww = 0; ww < 8; ++ww) a += red[ww][i][lane];
      g6[i] = a;
    }
    float gir = bih[d]     + g6[0];
    float giz = bih[256+d] + g6[1];
    float gin = bih[512+d] + g6[2];
    float ghr = bhh[d]     + g6[3];
    float ghz = bhh[256+d] + g6[4];
    float ghn = bhh[512+d] + g6[5];
    float hd = hT[d*64 + lane];
    float r  = sigmf(gir + ghr), z = sigmf(giz + ghz);
    float nn = tanhf_fast(gin + r*ghn);
    float hnew = (1.f - z)*nn + z*hd;
    if (isA) xrib[(size_t)lane*512 + 256 + d] = f2bf(hnew);
    else     htnT[(size_t)d*64 + lane]        = hnew;
  }
}

// F4: qp. 256 blocks (block = d), 4-wave k-split + reduce.
__global__ __launch_bounds__(256) void k_qp(
    const float* __restrict__ tWm, const float* __restrict__ htnT,
    float* __restrict__ qp)
{
  const int tid = threadIdx.x, w = tid >> 6, lane = tid & 63;
  const int d = blockIdx.x;
  __shared__ float red[4][64];
  float acc = 0.f;
  const float* wr = tWm + (size_t)d*256 + w*64;
  const float* xb = htnT + w*64*64 + lane;
  #pragma unroll
  for (int k = 0; k < 64; k += 4){
    float4 wv = *(const float4*)(wr + k);
    acc += wv.x*xb[(k+0)*64] + wv.y*xb[(k+1)*64]
         + wv.z*xb[(k+2)*64] + wv.w*xb[(k+3)*64];
  }
  red[w][lane] = acc;
  __syncthreads();
  if (w == 0)
    qp[lane*ND + d] = red[0][lane]+red[1][lane]+red[2][lane]+red[3][lane];
}

// ---------------------------------------------------------------------------
// K2: attention partial pass, batch-load / flat-reduce form.
// Grid (64 b, 32 chunks of 64 t), 256 thr. Wave owns 16 rows:
//   S1: issue ALL 16 row loads into regs (16 KB in flight/wave)
//   S2: per-lane partial scores, no cross-lane ops
//   S3: LDS transpose reduce (padded, conflict-free) + 2 shfl -> row weights
//   S4: ctx FMAs from in-register rows
// ---------------------------------------------------------------------------
__global__ __launch_bounds__(256) void k_attn_part(
    const float* __restrict__ enc, const float* __restrict__ qp,
    const float* __restrict__ tv,  float* __restrict__ attnP)
{
  const int tid = threadIdx.x, b = blockIdx.x, ch = blockIdx.y;
  const int w = tid >> 6, lane = tid & 63;
  const float C2  = 2.885390082f;      // 2*log2(e)
  const float L2E = 1.4426950408f;     // log2(e)
  __shared__ float qpL[256], vL[256];
  __shared__ float part[4][16][65];
  __shared__ float wbc[4][16];
  __shared__ float ctxL[4][256], sL[4];
  qpL[tid] = qp[b*ND + tid] * C2;
  vL[tid]  = tv[tid] * 2.f;
  __syncthreads();

  const float q0 = qpL[lane*4+0], q1 = qpL[lane*4+1], q2 = qpL[lane*4+2], q3 = qpL[lane*4+3];
  const float v0 = vL[lane*4+0],  v1 = vL[lane*4+1],  v2 = vL[lane*4+2],  v3 = vL[lane*4+3];
  float vs = 0.5f*(v0 + v1 + v2 + v3);
  #pragma unroll
  for (int off = 1; off < 64; off <<= 1) vs += __shfl_xor(vs, off);
  const float VS = vs;

  // S1: batch-load 16 rows (independent, all issued before first use)
  const float* base = enc + ((size_t)b*NTX + (size_t)ch*64 + w*16)*ND + lane*4;
  float4 ev[16];
  #pragma unroll
  for (int i = 0; i < 16; ++i) ev[i] = *(const float4*)(base + (size_t)i*ND);

  // S2: per-lane partial scores (pure VALU)
  #pragma unroll
  for (int i = 0; i < 16; ++i){
    float u0 = EXP2F(__builtin_fmaf(ev[i].x, C2, q0));
    float u1 = EXP2F(__builtin_fmaf(ev[i].y, C2, q1));
    float u2 = EXP2F(__builtin_fmaf(ev[i].z, C2, q2));
    float u3 = EXP2F(__builtin_fmaf(ev[i].w, C2, q3));
    part[w][i][lane] = v0*RCPF(u0 + 1.f) + v1*RCPF(u1 + 1.f)
                     + v2*RCPF(u2 + 1.f) + v3*RCPF(u3 + 1.f);
  }
  __syncthreads();

  // S3: reduce each row: lane -> (row rr, quarter q4); 16 adds + 2 shfl
  {
    const int rr = lane >> 2, q4 = lane & 3;
    float s = 0.f;
    #pragma unroll
    for (int i = 0; i < 16; ++i) s += part[w][rr][q4*16 + i];
    s += __shfl_xor(s, 1);
    s += __shfl_xor(s, 2);
    if (q4 == 0) wbc[w][rr] = EXP2F((VS - s) * L2E);
  }
  __syncthreads();

  // S4: weighted context from in-register rows
  float cx0=0.f, cx1=0.f, cx2=0.f, cx3=0.f, sacc=0.f;
  #pragma unroll
  for (int r = 0; r < 16; ++r){
    float wv = wbc[w][r];
    sacc += wv;
    cx0 = __builtin_fmaf(wv, ev[r].x, cx0);
    cx1 = __builtin_fmaf(wv, ev[r].y, cx1);
    cx2 = __builtin_fmaf(wv, ev[r].z, cx2);
    cx3 = __builtin_fmaf(wv, ev[r].w, cx3);
  }
  ctxL[w][lane*4+0]=cx0; ctxL[w][lane*4+1]=cx1;
  ctxL[w][lane*4+2]=cx2; ctxL[w][lane*4+3]=cx3;
  if (lane == 0) sL[w] = sacc;
  __syncthreads();
  float c = ctxL[0][tid]+ctxL[1][tid]+ctxL[2][tid]+ctxL[3][tid];
  float* dst = attnP + ((size_t)b*32 + ch)*257;
  dst[tid] = c;
  if (tid == 0) dst[256] = sL[0]+sL[1]+sL[2]+sL[3];
}

// K3: combine 32 chunk partials -> xrib rows 0..255 (bf16)
__global__ __launch_bounds__(256) void k_attn_red(
    const float* __restrict__ attnP, u16* __restrict__ xrib)
{
  const int tid = threadIdx.x, b = blockIdx.x;
  float c = 0.f, s = 0.f;
  for (int ch = 0; ch < 32; ++ch){
    const float* src = attnP + ((size_t)b*32 + ch)*257;
    c += src[tid]; s += src[256];
  }
  xrib[(size_t)b*512 + tid] = f2bf(c / s);
}

// ---------------------------------------------------------------------------
// MFMA GEMMs (A direct from global bf16, no LDS staging).
// D[b][col]: b = fb*16+(lane>>4)*4+reg, col = lane&15.
// ---------------------------------------------------------------------------

// ri projection: 64 blocks x 512 threads; 8 waves k-split (64 each).
__global__ __launch_bounds__(512) void k_mm_ri(
    const u16* __restrict__ xrib, const float* __restrict__ ri_w,
    const float* __restrict__ ri_b, float* __restrict__ x0,
    u16* __restrict__ x0b)
{
  __shared__ float Rs[8][4][4][65];
  const int tid = threadIdx.x, lane = tid & 63, w = tid >> 6;
  const int n0 = blockIdx.x * 16;
  f32x4 acc[4];
  #pragma unroll
  for (int i = 0; i < 4; ++i) acc[i] = (f32x4){0.f,0.f,0.f,0.f};
  const int kbase = w*64;
  const float* wr = ri_w + (size_t)(n0 + (lane & 15))*512 + kbase + (lane >> 4)*8;
  const u16* xs = xrib + (size_t)(lane & 15)*512 + kbase + (lane >> 4)*8;
  #pragma unroll
  for (int t = 0; t < 2; ++t){
    float4 wa = *(const float4*)(wr + t*32);
    float4 wb = *(const float4*)(wr + t*32 + 4);
    union { bf16x8 v; uint4 u; } bf;
    bf.u.x = pk2(wa.x,wa.y); bf.u.y = pk2(wa.z,wa.w);
    bf.u.z = pk2(wb.x,wb.y); bf.u.w = pk2(wb.z,wb.w);
    #pragma unroll
    for (int fb = 0; fb < 4; ++fb){
      union { bf16x8 v; uint4 u; } af;
      af.u = *(const uint4*)(xs + fb*16*512 + t*32);
      acc[fb] = __builtin_amdgcn_mfma_f32_16x16x32_bf16(af.v, bf.v, acc[fb], 0, 0, 0);
    }
  }
  #pragma unroll
  for (int fb = 0; fb < 4; ++fb)
    #pragma unroll
    for (int r = 0; r < 4; ++r) Rs[w][fb][r][lane] = acc[fb][r];
  __syncthreads();
  if (tid < 256){
    const int b = tid >> 2, c4 = (tid & 3)*4;
    const int fb = b >> 4, q = (b >> 2) & 3, reg = b & 3;
    #pragma unroll
    for (int cc = 0; cc < 4; ++cc){
      const int c = c4 + cc;
      float v = ri_b[n0 + c];
      #pragma unroll
      for (int ww = 0; ww < 8; ++ww) v += Rs[ww][fb][reg][q*16 + c];
      x0[(size_t)b*1024 + n0 + c]  = v;
      x0b[(size_t)b*1024 + n0 + c] = f2bf(v);
    }
  }
}

// ---------------------------------------------------------------------------
// Fused LSTM layer: 256 blocks x 1024 threads (16 waves). Block = 4 j-cols;
// 16 MFMA rows = 4 gates x 4 j. Waves 0..7: ih K-chunks of 128; 8..15: hh.
// LDS reduce, then same block applies cell + residual.
// ---------------------------------------------------------------------------
__global__ __launch_bounds__(1024) void k_lstm(
    const float* __restrict__ Wih, const float* __restrict__ Whh,
    const u16* __restrict__ xb, const u16* __restrict__ hb,
    const float* __restrict__ bih, const float* __restrict__ bhh,
    const float* __restrict__ c_in,
    const float* __restrict__ xin, float* __restrict__ xout,
    u16* __restrict__ xoutb)
{
  __shared__ float Rs[16][4][4][65];
  const int tid = threadIdx.x, lane = tid & 63, w = tid >> 6;
  const int j0 = blockIdx.x * 4;
  const float* W = (w < 8) ? Wih : Whh;
  const u16*   X = (w < 8) ? xb  : hb;
  const int kbase = (w & 7) * 128;

  f32x4 acc[4];
  #pragma unroll
  for (int i = 0; i < 4; ++i) acc[i] = (f32x4){0.f,0.f,0.f,0.f};
  const int r16 = lane & 15;
  const int g = r16 >> 2, jq = r16 & 3;
  const float* wr = W + (size_t)(g*1024 + j0 + jq)*1024 + kbase + (lane >> 4)*8;
  #pragma unroll
  for (int t = 0; t < 4; ++t){
    float4 wa = *(const float4*)(wr + t*32);
    float4 wb = *(const float4*)(wr + t*32 + 4);
    union { bf16x8 v; uint4 u; } bf;
    bf.u.x = pk2(wa.x,wa.y); bf.u.y = pk2(wa.z,wa.w);
    bf.u.z = pk2(wb.x,wb.y); bf.u.w = pk2(wb.z,wb.w);
    #pragma unroll
    for (int fb = 0; fb < 4; ++fb){
      union { bf16x8 v; uint4 u; } af;
      af.u = *(const uint4*)(X + (size_t)(fb*16 + r16)*1024 + kbase + (lane >> 4)*8 + t*32);
      acc[fb] = __builtin_amdgcn_mfma_f32_16x16x32_bf16(af.v, bf.v, acc[fb], 0, 0, 0);
    }
  }
  #pragma unroll
  for (int fb = 0; fb < 4; ++fb)
    #pragma unroll
    for (int r = 0; r < 4; ++r) Rs[w][fb][r][lane] = acc[fb][r];
  __syncthreads();

  if (tid < 256){
    const int b  = tid >> 2, jq2 = tid & 3;
    const int j  = j0 + jq2;
    const int fb = b >> 4, q = (b >> 2) & 3, reg = b & 3;
    float gate[4];
    #pragma unroll
    for (int gg = 0; gg < 4; ++gg){
      const int li = q*16 + gg*4 + jq2;
      float a = bih[gg*1024 + j] + bhh[gg*1024 + j];
      #pragma unroll
      for (int ww = 0; ww < 16; ++ww) a += Rs[ww][fb][reg][li];
      gate[gg] = a;
    }
    float ii = sigmf(gate[0]), ff = sigmf(gate[1]);
    float gv = tanhf_fast(gate[2]), oo = sigmf(gate[3]);
    float cc = ff * c_in[(size_t)b*1024 + j] + ii * gv;
    float hh = oo * tanhf_fast(cc);
    float xo = xin[(size_t)b*1024 + j] + hh;
    xout[(size_t)b*1024 + j]  = xo;
    xoutb[(size_t)b*1024 + j] = f2bf(xo);
  }
}

// K7: mel projection — only rows with col%20 < 2 of mp_w are needed.
__global__ __launch_bounds__(256) void k_mels(
    const float* __restrict__ x2, const float* __restrict__ mp_w,
    float* __restrict__ out)
{
  const int tid = threadIdx.x, b = blockIdx.x;
  __shared__ float xL[NL];
  #pragma unroll
  for (int i = 0; i < 4; ++i){
    int j = tid + 256*i;
    xL[j] = x2[(size_t)b*NL + j];
  }
  __syncthreads();
  if (tid < 160){
    int m = tid >> 1, r = tid & 1;
    float acc = dot_rowf(mp_w + (size_t)(m*20 + r)*NL, xL, 256);
    out[b*160 + tid] = acc;
  }
}

// ---------------------------------------------------------------------------
extern "C" void kernel_launch(void* const* d_in, const int* in_sizes, int n_in,
                              void* d_out, int out_size, void* d_ws, size_t ws_size,
                              hipStream_t stream)
{
  (void)in_sizes; (void)n_in; (void)out_size; (void)ws_size;
  const float* enc     = (const float*)d_in[0];
  const float* pre_in  = (const float*)d_in[2];
  const float* h_text  = (const float*)d_in[3];
  const float* h_attn  = (const float*)d_in[5];
  const float* h_r1    = (const float*)d_in[6];
  const float* h_r2    = (const float*)d_in[7];
  const float* c_r1    = (const float*)d_in[8];
  const float* c_r2    = (const float*)d_in[9];
  const float* cv_text = (const float*)d_in[10];
  const float* cv      = (const float*)d_in[12];
  const float* fc1_w   = (const float*)d_in[13];
  const float* fc1_b   = (const float*)d_in[14];
  const float* fc2_w   = (const float*)d_in[15];
  const float* fc2_b   = (const float*)d_in[16];
  const float* tWm     = (const float*)d_in[17];
  const float* tv      = (const float*)d_in[18];
  const float* t_wih   = (const float*)d_in[21];
  const float* t_whh   = (const float*)d_in[22];
  const float* t_bih   = (const float*)d_in[23];
  const float* t_bhh   = (const float*)d_in[24];
  const float* a_wih   = (const float*)d_in[29];
  const float* a_whh   = (const float*)d_in[30];
  const float* a_bih   = (const float*)d_in[31];
  const float* a_bhh   = (const float*)d_in[32];
  const float* ri_w    = (const float*)d_in[33];
  const float* ri_b    = (const float*)d_in[34];
  const float* l1_wih  = (const float*)d_in[35];
  const float* l1_whh  = (const float*)d_in[36];
  const float* l1_bih  = (const float*)d_in[37];
  const float* l1_bhh  = (const float*)d_in[38];
  const float* l2_wih  = (const float*)d_in[39];
  const float* l2_whh  = (const float*)d_in[40];
  const float* l2_bih  = (const float*)d_in[41];
  const float* l2_bhh  = (const float*)d_in[42];
  const float* mp_w    = (const float*)d_in[43];

  // workspace layout (float units, 16B-aligned regions), ~7 MB
  float* ws    = (float*)d_ws;
  float* qp    = ws;                    // 16384
  float* attnP = qp    + 16384;         // 64*32*257 = 526336
  float* x0    = attnP + 526336;        // 65536
  float* x1    = x0    + 65536;
  float* x2    = x1    + 65536;
  float* xtext = x2    + 65536;         // 24576
  float* xattn = xtext + 24576;         // 24576
  float* htT   = xattn + 24576;         // 16384
  float* haT   = htT   + 16384;
  float* htnT  = haT   + 16384;
  float* p1T   = htnT  + 16384;         // 16384
  u16*   hb1   = (u16*)(p1T + 16384);   // 65536 u16
  u16*   hb2   = hb1 + 65536;
  u16*   xrib  = hb2 + 65536;           // 64*512
  u16*   x0b   = xrib + 32768;          // 64*1024
  u16*   x1b   = x0b + 65536;
  u16*   x2b   = x1b + 65536;           // written, unused

  k_pre1<<<144, 256, 0, stream>>>(cv_text, cv, h_text, h_attn,
      pre_in, fc1_w, fc1_b, h_r1, h_r2,
      xtext, xattn, htT, haT, p1T, hb1, hb2);
  k_pre2<<<128, 256, 0, stream>>>(p1T, fc2_w, fc2_b, xtext, xattn);
  k_gru<<<512, 512, 0, stream>>>(t_wih, t_whh, t_bih, t_bhh,
      a_wih, a_whh, a_bih, a_bhh, xtext, xattn, htT, haT, htnT, xrib);
  k_qp<<<256, 256, 0, stream>>>(tWm, htnT, qp);

  k_attn_part<<<dim3(64,32), 256, 0, stream>>>(enc, qp, tv, attnP);
  k_attn_red<<<64, 256, 0, stream>>>(attnP, xrib);

  k_mm_ri<<<64, 512, 0, stream>>>(xrib, ri_w, ri_b, x0, x0b);

  k_lstm<<<256, 1024, 0, stream>>>(l1_wih, l1_whh, x0b, hb1,
      l1_bih, l1_bhh, c_r1, x0, x1, x1b);
  k_lstm<<<256, 1024, 0, stream>>>(l2_wih, l2_whh, x1b, hb2,
      l2_bih, l2_bhh, c_r2, x1, x2, x2b);

  k_mels<<<64, 256, 0, stream>>>(x2, mp_w, (float*)d_out);
}